// Round 1
// 578.803 us; speedup vs baseline: 1.0989x; 1.0989x over previous
//
#include <hip/hip_runtime.h>
#include <cstdint>

#define HH 128
#define SB 136  // padded bf16 LDS row stride for GEMM A tiles (272 B: 16B-aligned, 2-way max bank alias)
constexpr int cN_X   = 250000;
constexpr int cN_SRC = 50000;
constexpr int cN_Y   = 50000;
constexpr int cN_INT = 500000;
constexpr int cE_NODE = 1000000;
constexpr int cE_DOM  = 500000;

typedef __attribute__((ext_vector_type(8))) short bf16x8;
typedef __attribute__((ext_vector_type(4))) float f32x4;

__device__ __forceinline__ float bf2f(unsigned short s) {
  union { unsigned u; float f; } v; v.u = ((unsigned)s) << 16; return v.f;
}
__device__ __forceinline__ unsigned short f2bf(float f) {
  union { float f; unsigned u; } v; v.f = f;
  unsigned r = v.u + 0x7fffu + ((v.u >> 16) & 1u);  // RNE
  return (unsigned short)(r >> 16);
}

// ---------------- cast the three W matrices to bf16 (row-major) once
__global__ __launch_bounds__(256) void k_wcast(const float* __restrict__ w0,
                                               const float* __restrict__ w1,
                                               const float* __restrict__ w2,
                                               unsigned short* __restrict__ dst) {
  int i = blockIdx.x * 256 + threadIdx.x;
  int idx4 = i * 4;
  int mat = idx4 >> 14;
  int off = idx4 & 16383;
  const float* src = (mat == 0) ? w0 : (mat == 1) ? w1 : w2;
  float4 v = *(const float4*)(src + off);
  ushort4 u;
  u.x = f2bf(v.x); u.y = f2bf(v.y); u.z = f2bf(v.z); u.w = f2bf(v.w);
  *(ushort4*)(dst + (size_t)mat * 16384 + off) = u;
}

// ---------------- segment-sum of x by sorted domain_indicator -> xsum [N_SRC][H]
__global__ __launch_bounds__(256, 8) void k_segsum_x(const float* __restrict__ x,
                                                     const int* __restrict__ ind,
                                                     float* __restrict__ xsum) {
  __shared__ int sind[128];
  int tid = threadIdx.x, lane = tid & 63, wv = tid >> 6;
  int blk = blockIdx.x * 128;
  if (tid < 128 && blk + tid < cN_X) sind[tid] = ind[blk + tid];
  __syncthreads();
  int base = blk + wv * 32;
  if (base >= cN_X) return;
  int nrows = min(32, cN_X - base);
  int c0 = lane * 2;
  float a0 = 0.f, a1 = 0.f;
  int cur = sind[wv * 32];
  bool inside = false;
  for (int r0 = 0; r0 < nrows; r0 += 8) {
    int nb = min(8, nrows - r0);
    float2 v[8];
#pragma unroll
    for (int k = 0; k < 8; k++)
      if (k < nb) v[k] = *(const float2*)(x + (size_t)(base + r0 + k) * HH + c0);
#pragma unroll
    for (int k = 0; k < 8; k++) {
      if (k < nb) {
        int s = sind[wv * 32 + r0 + k];
        if (s != cur) {
          if (inside) {
            xsum[(size_t)cur * HH + c0] = a0;
            xsum[(size_t)cur * HH + c0 + 1] = a1;
          } else {
            atomicAdd(&xsum[(size_t)cur * HH + c0], a0);
            atomicAdd(&xsum[(size_t)cur * HH + c0 + 1], a1);
          }
          cur = s; a0 = 0.f; a1 = 0.f; inside = true;
        }
        a0 += v[k].x; a1 += v[k].y;
      }
    }
  }
  atomicAdd(&xsum[(size_t)cur * HH + c0], a0);
  atomicAdd(&xsum[(size_t)cur * HH + c0 + 1], a1);
}

// ---------------- MFMA helpers
__device__ __forceinline__ void load_bfrags(const unsigned short* __restrict__ Wbf,
                                            int wv, int lane, bf16x8 bfrag[2][4]) {
  int cbase = wv * 32 + (lane & 15);
  int krow = (lane >> 4) * 8;
#pragma unroll
  for (int ct = 0; ct < 2; ct++)
#pragma unroll
    for (int kt = 0; kt < 4; kt++)
      bfrag[ct][kt] = *(const bf16x8*)(Wbf + (size_t)(cbase + ct * 16) * HH + kt * 32 + krow);
}

// ---------------- outb[M][128] (bf16) = A[M][128] @ W^T via MFMA
// A staged in LDS as bf16 (converted once at staging, not per-fragment).
__global__ __launch_bounds__(256, 4) void k_gemm128b(const float* __restrict__ A,
                                                     const unsigned short* __restrict__ Wbf,
                                                     unsigned short* __restrict__ outb, int M) {
  __shared__ unsigned short sA[64 * SB];
  int tid = threadIdx.x, lane = tid & 63, wv = tid >> 6;
  int row0 = blockIdx.x * 64;
  int rows = min(64, M - row0);
  bf16x8 bfrag[2][4];
  load_bfrags(Wbf, wv, lane, bfrag);
  // stage 64x128 f32 -> bf16 LDS: 8192 elems / 256 thr = 32/thread = 4 x bf16x8
#pragma unroll
  for (int it = 0; it < 4; it++) {
    int g = it * 2048 + tid * 8;
    int r = g >> 7, c = g & 127;
    bf16x8 v = {0, 0, 0, 0, 0, 0, 0, 0};
    if (r < rows) {
      float4 f0 = *(const float4*)(A + (size_t)(row0 + r) * HH + c);
      float4 f1 = *(const float4*)(A + (size_t)(row0 + r) * HH + c + 4);
      v[0] = (short)f2bf(f0.x); v[1] = (short)f2bf(f0.y);
      v[2] = (short)f2bf(f0.z); v[3] = (short)f2bf(f0.w);
      v[4] = (short)f2bf(f1.x); v[5] = (short)f2bf(f1.y);
      v[6] = (short)f2bf(f1.z); v[7] = (short)f2bf(f1.w);
    }
    *(bf16x8*)(&sA[r * SB + c]) = v;
  }
  __syncthreads();
  int m = lane & 15, q = lane >> 4;
  f32x4 acc[4][2];
#pragma unroll
  for (int rt = 0; rt < 4; rt++)
#pragma unroll
    for (int ct = 0; ct < 2; ct++) acc[rt][ct] = (f32x4){0.f, 0.f, 0.f, 0.f};
#pragma unroll
  for (int kt = 0; kt < 4; kt++) {
    int kof = kt * 32 + q * 8;
#pragma unroll
    for (int rt = 0; rt < 4; rt++) {
      bf16x8 af = *(const bf16x8*)(&sA[(rt * 16 + m) * SB + kof]);
      acc[rt][0] = __builtin_amdgcn_mfma_f32_16x16x32_bf16(af, bfrag[0][kt], acc[rt][0], 0, 0, 0);
      acc[rt][1] = __builtin_amdgcn_mfma_f32_16x16x32_bf16(af, bfrag[1][kt], acc[rt][1], 0, 0, 0);
    }
  }
  __syncthreads();
  unsigned short* sC = sA;
#pragma unroll
  for (int rt = 0; rt < 4; rt++)
#pragma unroll
    for (int ct = 0; ct < 2; ct++)
#pragma unroll
      for (int rg = 0; rg < 4; rg++) {
        int r = rt * 16 + q * 4 + rg;
        sC[r * HH + wv * 32 + ct * 16 + m] = f2bf(acc[rt][ct][rg]);
      }
  __syncthreads();
  for (int i = tid; i < rows * 16; i += 256) {
    int r = i >> 4, g = i & 15;
    ((uint4*)(outb + (size_t)(row0 + r) * HH))[g] = ((const uint4*)(sC + r * HH))[g];
  }
}

// ---------------- bnd via linear boundary marking: bnd[e] = first j with ii[j] >= e
__global__ __launch_bounds__(256) void k_bounds(const int* __restrict__ ii,
                                                int* __restrict__ bnd) {
  int j = blockIdx.x * 256 + threadIdx.x;
  if (j > cE_NODE) return;
  if (j == cE_NODE) {
    int a = ii[cE_NODE - 1];
    for (int e = a + 1; e <= cN_INT; ++e) bnd[e] = cE_NODE;
    return;
  }
  int b = ii[j];
  int a = (j == 0) ? -1 : ii[j - 1];
  for (int e = a + 1; e <= b; ++e) bnd[e] = j;
}

// ---------------- CSR build for dme1 (offs + inverse permutation inv[e]=pos)
__global__ void k_hist(const int* __restrict__ dme1, int* __restrict__ cnt) {
  int e = blockIdx.x * blockDim.x + threadIdx.x;
  if (e < cE_DOM) atomicAdd(&cnt[dme1[e]], 1);
}
__global__ __launch_bounds__(256) void k_scan1(const int* __restrict__ cnt,
                                               int* __restrict__ bsum, int* __restrict__ excl) {
  __shared__ int buf[256];
  int i = blockIdx.x * 256 + threadIdx.x;
  int v = (i < cN_SRC) ? cnt[i] : 0;
  buf[threadIdx.x] = v; __syncthreads();
  for (int d = 1; d < 256; d <<= 1) {
    int t = (threadIdx.x >= d) ? buf[threadIdx.x - d] : 0;
    __syncthreads();
    buf[threadIdx.x] += t;
    __syncthreads();
  }
  if (i < cN_SRC) excl[i] = buf[threadIdx.x] - v;
  if (threadIdx.x == 255) bsum[blockIdx.x] = buf[255];
}
__global__ __launch_bounds__(256) void k_scan2(int* __restrict__ bsum, int nb) {
  __shared__ int buf[256];
  int v = (threadIdx.x < nb) ? bsum[threadIdx.x] : 0;
  buf[threadIdx.x] = v; __syncthreads();
  for (int d = 1; d < 256; d <<= 1) {
    int t = (threadIdx.x >= d) ? buf[threadIdx.x - d] : 0;
    __syncthreads();
    buf[threadIdx.x] += t;
    __syncthreads();
  }
  if (threadIdx.x < nb) bsum[threadIdx.x] = buf[threadIdx.x] - v;
}
__global__ void k_scan3(const int* __restrict__ excl, const int* __restrict__ bsum,
                        int* __restrict__ offs, int* __restrict__ cursor) {
  int i = blockIdx.x * 256 + threadIdx.x;
  if (i < cN_SRC) { int o = excl[i] + bsum[i >> 8]; offs[i] = o; cursor[i] = o; }
  else if (i == cN_SRC) offs[cN_SRC] = cE_DOM;
}
__global__ void k_scatter(const int* __restrict__ dme1, int* __restrict__ cursor,
                          int* __restrict__ inv) {
  int e = blockIdx.x * blockDim.x + threadIdx.x;
  if (e < cE_DOM) inv[e] = atomicAdd(&cursor[dme1[e]], 1);
}

// ---------------- edge kernel v3: wave-per-edge (8 edges/wave).
// Latency-bound fix: batch-issue ALL per-edge loads (phase A: xs/yy/idxv, 24 in
// flight), then depth-2 software pipeline for the xw row gathers (3 rotating
// 4-reg buffers). Gather bases scalarized via readlane/readfirstlane so address
// math is SALU, not per-lane 64-bit VALU. msg written at CSR position (nt store).
#define EDGE_ISSUE(I, B)                                                     \
  do {                                                                       \
    int le_ = wv * 8 + (I);                                                  \
    int n_ = __builtin_amdgcn_readfirstlane(sB[le_ + 1] - sB[le_]);          \
    _Pragma("unroll")                                                        \
    for (int k_ = 0; k_ < 4; k_++)                                           \
      if (k_ < n_) {                                                         \
        int r_ = __builtin_amdgcn_readlane(idxv[I], k_);                     \
        ub[B][k_] = xwu[(size_t)r_ * 64 + lane];                             \
      }                                                                      \
  } while (0)

#define EDGE_CONSUME(I, B)                                                   \
  do {                                                                       \
    int le_ = wv * 8 + (I);                                                  \
    int j0_ = __builtin_amdgcn_readfirstlane(sB[le_]);                       \
    int n_ = __builtin_amdgcn_readfirstlane(sB[le_ + 1]) - j0_;              \
    int pos_ = __builtin_amdgcn_readfirstlane(sP[le_]);                      \
    float a0_ = 0.f, a1_ = 0.f;                                              \
    _Pragma("unroll")                                                        \
    for (int k_ = 0; k_ < 4; k_++)                                           \
      if (k_ < n_) {                                                         \
        a0_ += bf2f(ub[B][k_] & 0xffff);                                     \
        a1_ += bf2f(ub[B][k_] >> 16);                                        \
      }                                                                      \
    if (n_ > 4) {                                                            \
      for (int k_ = 4; k_ < n_; k_++) {                                      \
        int r_ = (k_ < 64) ? __builtin_amdgcn_readlane(idxv[I], k_)          \
                           : nme0[j0_ + k_];                                 \
        unsigned uu_ = xwu[(size_t)r_ * 64 + lane];                          \
        a0_ += bf2f(uu_ & 0xffff);                                           \
        a1_ += bf2f(uu_ >> 16);                                              \
      }                                                                      \
    }                                                                        \
    float m0_ = a0_ + bf2f(xs[I] & 0xffff) + bf2f(yy[I] & 0xffff);           \
    float m1_ = a1_ + bf2f(xs[I] >> 16) + bf2f(yy[I] >> 16);                 \
    unsigned um_ = ((unsigned)f2bf(m1_) << 16) | (unsigned)f2bf(m0_);        \
    __builtin_nontemporal_store(um_, &msgu[(size_t)pos_ * 64 + lane]);       \
    s0 += m0_; q0 += m0_ * m0_; s1 += m1_; q1 += m1_ * m1_;                  \
  } while (0)

__global__ __launch_bounds__(256, 8) void k_edge2(
    const unsigned* __restrict__ xwu, const int* __restrict__ nme0,
    const int* __restrict__ bnd,
    const unsigned* __restrict__ xslu, const unsigned* __restrict__ ylu,
    const int* __restrict__ dme0, const int* __restrict__ dme1,
    const int* __restrict__ inv,
    unsigned* __restrict__ msgu, float* __restrict__ partials) {
  __shared__ int sB[33], sD0[32], sD1[32], sP[32];
  __shared__ float sBN[1024];
  int tid = threadIdx.x, lane = tid & 63, wv = tid >> 6;
  int e0 = blockIdx.x * 32;
  if (tid < 33) sB[tid] = bnd[e0 + tid];
  else if (tid < 96 && tid >= 64) sD0[tid - 64] = dme0[e0 + tid - 64];
  else if (tid < 160 && tid >= 128) sD1[tid - 128] = dme1[e0 + tid - 128];
  else if (tid < 224 && tid >= 192) sP[tid - 192] = inv[e0 + tid - 192];
  __syncthreads();

  // Phase A: issue xs/yy/idxv for all 8 edges (24 independent loads in flight)
  unsigned xs[8], yy[8];
  int idxv[8];
#pragma unroll
  for (int i = 0; i < 8; i++) {
    int le = wv * 8 + i;
    int s = __builtin_amdgcn_readfirstlane(sD0[le]);
    int t = __builtin_amdgcn_readfirstlane(sD1[le]);
    int j0 = __builtin_amdgcn_readfirstlane(sB[le]);
    int n = __builtin_amdgcn_readfirstlane(sB[le + 1]) - j0;
    xs[i] = xslu[(size_t)s * 64 + lane];
    yy[i] = ylu[(size_t)t * 64 + lane];
    idxv[i] = (lane < n) ? nme0[j0 + lane] : 0;
  }

  float s0 = 0.f, q0 = 0.f, s1 = 0.f, q1 = 0.f;
  unsigned ub[3][4];
  EDGE_ISSUE(0, 0);
  EDGE_ISSUE(1, 1);
  EDGE_ISSUE(2, 2);
  EDGE_CONSUME(0, 0);
  EDGE_ISSUE(3, 0);
  EDGE_CONSUME(1, 1);
  EDGE_ISSUE(4, 1);
  EDGE_CONSUME(2, 2);
  EDGE_ISSUE(5, 2);
  EDGE_CONSUME(3, 0);
  EDGE_ISSUE(6, 0);
  EDGE_CONSUME(4, 1);
  EDGE_ISSUE(7, 1);
  EDGE_CONSUME(5, 2);
  EDGE_CONSUME(6, 0);
  EDGE_CONSUME(7, 1);

  *(float4*)(&sBN[wv * 256 + lane * 4]) = make_float4(s0, q0, s1, q1);
  __syncthreads();
  float v = sBN[tid] + sBN[256 + tid] + sBN[512 + tid] + sBN[768 + tid];
  __builtin_nontemporal_store(v, &partials[(size_t)blockIdx.x * 256 + tid]);
}

// ---------------- BN stat reduction + scale/shift
__global__ __launch_bounds__(256) void k_bnred1(const float* __restrict__ partials,
                                                float* __restrict__ part2, int nb) {
  float s = 0.f;
  for (int b = blockIdx.x; b < nb; b += 64) s += partials[(size_t)b * 256 + threadIdx.x];
  part2[blockIdx.x * 256 + threadIdx.x] = s;
}
__global__ __launch_bounds__(256) void k_bnfinal(const float* __restrict__ part2,
                                                 const float* __restrict__ bnw,
                                                 const float* __restrict__ bnb,
                                                 float* __restrict__ ss) {
  __shared__ float L[256];
  float s = 0.f;
  for (int b = 0; b < 64; b++) s += part2[b * 256 + threadIdx.x];
  L[threadIdx.x] = s; __syncthreads();
  if (threadIdx.x < HH) {
    int c = threadIdx.x;
    float sum = L[2 * c], sq = L[2 * c + 1];
    float mean = sum / (float)cE_DOM;
    float var = sq / (float)cE_DOM - mean * mean;
    float sc = bnw[c] * rsqrtf(var + 1e-5f);
    float sh = bnb[c] - mean * sc;
    ss[2 * c] = sc; ss[2 * c + 1] = sh;
  }
}

// ---------------- final v3: msg is CSR-ordered, so each target reads a
// CONTIGUOUS run of rows [offs[t], offs[t+1]). 8-deep load batching.
__global__ __launch_bounds__(256, 8) void k_out2(const unsigned* __restrict__ msgu,
                                                 const int* __restrict__ offs,
                                                 const float* __restrict__ ss,
                                                 float* __restrict__ out) {
  int wv = threadIdx.x >> 6, lane = threadIdx.x & 63;
  int t = blockIdx.x * 4 + wv;
  if (t >= cN_Y) return;
  int c0 = lane * 2;
  float sc0 = ss[c0 * 2 + 0], sh0 = ss[c0 * 2 + 1];
  float sc1 = ss[c0 * 2 + 2], sh1 = ss[c0 * 2 + 3];
  int j0 = __builtin_amdgcn_readfirstlane(offs[t]);
  int j1 = __builtin_amdgcn_readfirstlane(offs[t + 1]);
  float a0 = 0.f, a1 = 0.f;
  int p = j0;
  for (; p + 8 <= j1; p += 8) {
    unsigned m[8];
#pragma unroll
    for (int k = 0; k < 8; k++) m[k] = msgu[(size_t)(p + k) * 64 + lane];
#pragma unroll
    for (int k = 0; k < 8; k++) {
      a0 += fmaxf(fmaf(bf2f(m[k] & 0xffff), sc0, sh0), 0.f);
      a1 += fmaxf(fmaf(bf2f(m[k] >> 16), sc1, sh1), 0.f);
    }
  }
  if (p + 4 <= j1) {
    unsigned m[4];
#pragma unroll
    for (int k = 0; k < 4; k++) m[k] = msgu[(size_t)(p + k) * 64 + lane];
#pragma unroll
    for (int k = 0; k < 4; k++) {
      a0 += fmaxf(fmaf(bf2f(m[k] & 0xffff), sc0, sh0), 0.f);
      a1 += fmaxf(fmaf(bf2f(m[k] >> 16), sc1, sh1), 0.f);
    }
    p += 4;
  }
  for (; p < j1; p++) {
    unsigned m = msgu[(size_t)p * 64 + lane];
    a0 += fmaxf(fmaf(bf2f(m & 0xffff), sc0, sh0), 0.f);
    a1 += fmaxf(fmaf(bf2f(m >> 16), sc1, sh1), 0.f);
  }
  *(float2*)(out + (size_t)t * HH + c0) = make_float2(a0, a1);
}

extern "C" void kernel_launch(void* const* d_in, const int* in_sizes, int n_in,
                              void* d_out, int out_size, void* d_ws, size_t ws_size,
                              hipStream_t stream) {
  const float* x     = (const float*)d_in[0];
  const float* y     = (const float*)d_in[1];
  const int* dom_ind = (const int*)d_in[2];
  const int* nme     = (const int*)d_in[3];
  const int* ii      = (const int*)d_in[4];
  const int* dme     = (const int*)d_in[5];
  const float* Wxsum = (const float*)d_in[6];
  const float* Wxint = (const float*)d_in[7];
  const float* Wy    = (const float*)d_in[8];
  const float* bnw   = (const float*)d_in[9];
  const float* bnb   = (const float*)d_in[10];
  float* out = (float*)d_out;

  char* ws = (char*)d_ws;
  size_t o = 0;
  auto alloc = [&](size_t bytes) -> void* {
    void* p = ws + o;
    o = (o + bytes + 255) & ~(size_t)255;
    return p;
  };
  float* xsum   = (float*)alloc((size_t)cN_SRC * HH * 4);
  unsigned short* xsl = (unsigned short*)alloc((size_t)cN_SRC * HH * 2);
  unsigned short* ylin = (unsigned short*)alloc((size_t)cN_Y * HH * 2);
  unsigned short* xw = (unsigned short*)alloc((size_t)cN_X * HH * 2);
  unsigned short* msg = (unsigned short*)alloc((size_t)cE_DOM * HH * 2);
  int* bnd      = (int*)alloc((size_t)(cN_INT + 1) * 4);
  int* cnt      = (int*)alloc((size_t)cN_SRC * 4);
  int* excl     = (int*)alloc((size_t)cN_SRC * 4);
  int* bsum     = (int*)alloc(256 * 4);
  int* offs     = (int*)alloc((size_t)(cN_SRC + 1) * 4);
  int* cursor   = (int*)alloc((size_t)cN_SRC * 4);
  int* inv      = (int*)alloc((size_t)cE_DOM * 4);
  const int neb = cE_DOM / 32;  // 15625 edge blocks
  float* partials = (float*)alloc((size_t)neb * 256 * 4);
  float* part2  = (float*)alloc(64 * 256 * 4);
  float* ssbuf  = (float*)alloc(256 * 4);
  unsigned short* Wbf = (unsigned short*)alloc(3 * 16384 * 2);

  hipMemsetAsync(xsum, 0, (size_t)cN_SRC * HH * 4, stream);
  hipMemsetAsync(cnt, 0, (size_t)cN_SRC * 4, stream);

  k_wcast<<<48, 256, 0, stream>>>(Wxsum, Wy, Wxint, Wbf);
  k_segsum_x<<<(cN_X + 127) / 128, 256, 0, stream>>>(x, dom_ind, xsum);
  k_gemm128b<<<(cN_X + 63) / 64, 256, 0, stream>>>(x, Wbf + 32768, xw, cN_X);
  k_gemm128b<<<(cN_SRC + 63) / 64, 256, 0, stream>>>(xsum, Wbf, xsl, cN_SRC);
  k_gemm128b<<<(cN_Y + 63) / 64, 256, 0, stream>>>(y, Wbf + 16384, ylin, cN_Y);
  k_bounds<<<(cE_NODE + 1 + 255) / 256, 256, 0, stream>>>(ii, bnd);
  k_hist<<<(cE_DOM + 255) / 256, 256, 0, stream>>>(dme + cE_DOM, cnt);
  k_scan1<<<(cN_SRC + 255) / 256, 256, 0, stream>>>(cnt, bsum, excl);
  k_scan2<<<1, 256, 0, stream>>>(bsum, (cN_SRC + 255) / 256);
  k_scan3<<<(cN_SRC + 1 + 255) / 256, 256, 0, stream>>>(excl, bsum, offs, cursor);
  k_scatter<<<(cE_DOM + 255) / 256, 256, 0, stream>>>(dme + cE_DOM, cursor, inv);
  k_edge2<<<neb, 256, 0, stream>>>((const unsigned*)xw, nme, bnd,
                                   (const unsigned*)xsl, (const unsigned*)ylin,
                                   dme, dme + cE_DOM, inv,
                                   (unsigned*)msg, partials);
  k_bnred1<<<64, 256, 0, stream>>>(partials, part2, neb);
  k_bnfinal<<<1, 256, 0, stream>>>(part2, bnw, bnb, ssbuf);
  k_out2<<<(cN_Y + 3) / 4, 256, 0, stream>>>((const unsigned*)msg, offs, ssbuf, out);
}

// Round 2
// 478.463 us; speedup vs baseline: 1.3293x; 1.2097x over previous
//
#include <hip/hip_runtime.h>
#include <cstdint>

#define HH 128
#define SB 136  // padded bf16 LDS row stride for GEMM A tiles (272 B: 16B-aligned, 2-way max bank alias)
constexpr int cN_X   = 250000;
constexpr int cN_SRC = 50000;
constexpr int cN_Y   = 50000;
constexpr int cN_INT = 500000;
constexpr int cE_NODE = 1000000;
constexpr int cE_DOM  = 500000;

typedef __attribute__((ext_vector_type(8))) short bf16x8;
typedef __attribute__((ext_vector_type(4))) float f32x4;

__device__ __forceinline__ float bf2f(unsigned short s) {
  union { unsigned u; float f; } v; v.u = ((unsigned)s) << 16; return v.f;
}
__device__ __forceinline__ unsigned short f2bf(float f) {
  union { float f; unsigned u; } v; v.f = f;
  unsigned r = v.u + 0x7fffu + ((v.u >> 16) & 1u);  // RNE
  return (unsigned short)(r >> 16);
}

// ---------------- cast the three W matrices to bf16 (row-major) once
__global__ __launch_bounds__(256) void k_wcast(const float* __restrict__ w0,
                                               const float* __restrict__ w1,
                                               const float* __restrict__ w2,
                                               unsigned short* __restrict__ dst) {
  int i = blockIdx.x * 256 + threadIdx.x;
  int idx4 = i * 4;
  int mat = idx4 >> 14;
  int off = idx4 & 16383;
  const float* src = (mat == 0) ? w0 : (mat == 1) ? w1 : w2;
  float4 v = *(const float4*)(src + off);
  ushort4 u;
  u.x = f2bf(v.x); u.y = f2bf(v.y); u.z = f2bf(v.z); u.w = f2bf(v.w);
  *(ushort4*)(dst + (size_t)mat * 16384 + off) = u;
}

// ---------------- segment-sum of x by sorted domain_indicator -> xsum [N_SRC][H]
__global__ __launch_bounds__(256, 8) void k_segsum_x(const float* __restrict__ x,
                                                     const int* __restrict__ ind,
                                                     float* __restrict__ xsum) {
  __shared__ int sind[128];
  int tid = threadIdx.x, lane = tid & 63, wv = tid >> 6;
  int blk = blockIdx.x * 128;
  if (tid < 128 && blk + tid < cN_X) sind[tid] = ind[blk + tid];
  __syncthreads();
  int base = blk + wv * 32;
  if (base >= cN_X) return;
  int nrows = min(32, cN_X - base);
  int c0 = lane * 2;
  float a0 = 0.f, a1 = 0.f;
  int cur = sind[wv * 32];
  bool inside = false;
  for (int r0 = 0; r0 < nrows; r0 += 8) {
    int nb = min(8, nrows - r0);
    float2 v[8];
#pragma unroll
    for (int k = 0; k < 8; k++)
      if (k < nb) v[k] = *(const float2*)(x + (size_t)(base + r0 + k) * HH + c0);
#pragma unroll
    for (int k = 0; k < 8; k++) {
      if (k < nb) {
        int s = sind[wv * 32 + r0 + k];
        if (s != cur) {
          if (inside) {
            xsum[(size_t)cur * HH + c0] = a0;
            xsum[(size_t)cur * HH + c0 + 1] = a1;
          } else {
            atomicAdd(&xsum[(size_t)cur * HH + c0], a0);
            atomicAdd(&xsum[(size_t)cur * HH + c0 + 1], a1);
          }
          cur = s; a0 = 0.f; a1 = 0.f; inside = true;
        }
        a0 += v[k].x; a1 += v[k].y;
      }
    }
  }
  atomicAdd(&xsum[(size_t)cur * HH + c0], a0);
  atomicAdd(&xsum[(size_t)cur * HH + c0 + 1], a1);
}

// ---------------- MFMA helpers
__device__ __forceinline__ void load_bfrags(const unsigned short* __restrict__ Wbf,
                                            int wv, int lane, bf16x8 bfrag[2][4]) {
  int cbase = wv * 32 + (lane & 15);
  int krow = (lane >> 4) * 8;
#pragma unroll
  for (int ct = 0; ct < 2; ct++)
#pragma unroll
    for (int kt = 0; kt < 4; kt++)
      bfrag[ct][kt] = *(const bf16x8*)(Wbf + (size_t)(cbase + ct * 16) * HH + kt * 32 + krow);
}

// ---------------- outb[M][128] (bf16) = A[M][128] @ W^T via MFMA
// A staged in LDS as bf16 (converted once at staging, not per-fragment).
__global__ __launch_bounds__(256, 4) void k_gemm128b(const float* __restrict__ A,
                                                     const unsigned short* __restrict__ Wbf,
                                                     unsigned short* __restrict__ outb, int M) {
  __shared__ unsigned short sA[64 * SB];
  int tid = threadIdx.x, lane = tid & 63, wv = tid >> 6;
  int row0 = blockIdx.x * 64;
  int rows = min(64, M - row0);
  bf16x8 bfrag[2][4];
  load_bfrags(Wbf, wv, lane, bfrag);
  // stage 64x128 f32 -> bf16 LDS: 8192 elems / 256 thr = 32/thread = 4 x bf16x8
#pragma unroll
  for (int it = 0; it < 4; it++) {
    int g = it * 2048 + tid * 8;
    int r = g >> 7, c = g & 127;
    bf16x8 v = {0, 0, 0, 0, 0, 0, 0, 0};
    if (r < rows) {
      float4 f0 = *(const float4*)(A + (size_t)(row0 + r) * HH + c);
      float4 f1 = *(const float4*)(A + (size_t)(row0 + r) * HH + c + 4);
      v[0] = (short)f2bf(f0.x); v[1] = (short)f2bf(f0.y);
      v[2] = (short)f2bf(f0.z); v[3] = (short)f2bf(f0.w);
      v[4] = (short)f2bf(f1.x); v[5] = (short)f2bf(f1.y);
      v[6] = (short)f2bf(f1.z); v[7] = (short)f2bf(f1.w);
    }
    *(bf16x8*)(&sA[r * SB + c]) = v;
  }
  __syncthreads();
  int m = lane & 15, q = lane >> 4;
  f32x4 acc[4][2];
#pragma unroll
  for (int rt = 0; rt < 4; rt++)
#pragma unroll
    for (int ct = 0; ct < 2; ct++) acc[rt][ct] = (f32x4){0.f, 0.f, 0.f, 0.f};
#pragma unroll
  for (int kt = 0; kt < 4; kt++) {
    int kof = kt * 32 + q * 8;
#pragma unroll
    for (int rt = 0; rt < 4; rt++) {
      bf16x8 af = *(const bf16x8*)(&sA[(rt * 16 + m) * SB + kof]);
      acc[rt][0] = __builtin_amdgcn_mfma_f32_16x16x32_bf16(af, bfrag[0][kt], acc[rt][0], 0, 0, 0);
      acc[rt][1] = __builtin_amdgcn_mfma_f32_16x16x32_bf16(af, bfrag[1][kt], acc[rt][1], 0, 0, 0);
    }
  }
  __syncthreads();
  unsigned short* sC = sA;
#pragma unroll
  for (int rt = 0; rt < 4; rt++)
#pragma unroll
    for (int ct = 0; ct < 2; ct++)
#pragma unroll
      for (int rg = 0; rg < 4; rg++) {
        int r = rt * 16 + q * 4 + rg;
        sC[r * HH + wv * 32 + ct * 16 + m] = f2bf(acc[rt][ct][rg]);
      }
  __syncthreads();
  for (int i = tid; i < rows * 16; i += 256) {
    int r = i >> 4, g = i & 15;
    ((uint4*)(outb + (size_t)(row0 + r) * HH))[g] = ((const uint4*)(sC + r * HH))[g];
  }
}

// ---------------- bnd via linear boundary marking: bnd[e] = first j with ii[j] >= e
__global__ __launch_bounds__(256) void k_bounds(const int* __restrict__ ii,
                                                int* __restrict__ bnd) {
  int j = blockIdx.x * 256 + threadIdx.x;
  if (j > cE_NODE) return;
  if (j == cE_NODE) {
    int a = ii[cE_NODE - 1];
    for (int e = a + 1; e <= cN_INT; ++e) bnd[e] = cE_NODE;
    return;
  }
  int b = ii[j];
  int a = (j == 0) ? -1 : ii[j - 1];
  for (int e = a + 1; e <= b; ++e) bnd[e] = j;
}

// ---------------- CSR build for dme1 (offs + inverse permutation inv[e]=pos)
__global__ void k_hist(const int* __restrict__ dme1, int* __restrict__ cnt) {
  int e = blockIdx.x * blockDim.x + threadIdx.x;
  if (e < cE_DOM) atomicAdd(&cnt[dme1[e]], 1);
}
__global__ __launch_bounds__(256) void k_scan1(const int* __restrict__ cnt,
                                               int* __restrict__ bsum, int* __restrict__ excl) {
  __shared__ int buf[256];
  int i = blockIdx.x * 256 + threadIdx.x;
  int v = (i < cN_SRC) ? cnt[i] : 0;
  buf[threadIdx.x] = v; __syncthreads();
  for (int d = 1; d < 256; d <<= 1) {
    int t = (threadIdx.x >= d) ? buf[threadIdx.x - d] : 0;
    __syncthreads();
    buf[threadIdx.x] += t;
    __syncthreads();
  }
  if (i < cN_SRC) excl[i] = buf[threadIdx.x] - v;
  if (threadIdx.x == 255) bsum[blockIdx.x] = buf[255];
}
__global__ __launch_bounds__(256) void k_scan2(int* __restrict__ bsum, int nb) {
  __shared__ int buf[256];
  int v = (threadIdx.x < nb) ? bsum[threadIdx.x] : 0;
  buf[threadIdx.x] = v; __syncthreads();
  for (int d = 1; d < 256; d <<= 1) {
    int t = (threadIdx.x >= d) ? buf[threadIdx.x - d] : 0;
    __syncthreads();
    buf[threadIdx.x] += t;
    __syncthreads();
  }
  if (threadIdx.x < nb) bsum[threadIdx.x] = buf[threadIdx.x] - v;
}
__global__ void k_scan3(const int* __restrict__ excl, const int* __restrict__ bsum,
                        int* __restrict__ offs, int* __restrict__ cursor) {
  int i = blockIdx.x * 256 + threadIdx.x;
  if (i < cN_SRC) { int o = excl[i] + bsum[i >> 8]; offs[i] = o; cursor[i] = o; }
  else if (i == cN_SRC) offs[cN_SRC] = cE_DOM;
}
__global__ void k_scatter(const int* __restrict__ dme1, int* __restrict__ cursor,
                          int* __restrict__ inv) {
  int e = blockIdx.x * blockDim.x + threadIdx.x;
  if (e < cE_DOM) inv[e] = atomicAdd(&cursor[dme1[e]], 1);
}

// ---------------- edge kernel v4: wave-per-edge (8 edges/wave).
// Batch-issue all per-edge loads (phase A), depth-2 software pipeline for the
// xw row gathers. Gather bases scalarized via readlane/readfirstlane. BN stats
// reduced in-block then atomically folded into a 64-slot spread accumulator
// (no 16 MB partials round-trip; k_bnred1 eliminated).
#define EDGE_ISSUE(I, B)                                                     \
  do {                                                                       \
    int le_ = wv * 8 + (I);                                                  \
    int n_ = __builtin_amdgcn_readfirstlane(sB[le_ + 1] - sB[le_]);          \
    _Pragma("unroll")                                                        \
    for (int k_ = 0; k_ < 4; k_++)                                           \
      if (k_ < n_) {                                                         \
        int r_ = __builtin_amdgcn_readlane(idxv[I], k_);                     \
        ub[B][k_] = xwu[(size_t)r_ * 64 + lane];                             \
      }                                                                      \
  } while (0)

#define EDGE_CONSUME(I, B)                                                   \
  do {                                                                       \
    int le_ = wv * 8 + (I);                                                  \
    int j0_ = __builtin_amdgcn_readfirstlane(sB[le_]);                       \
    int n_ = __builtin_amdgcn_readfirstlane(sB[le_ + 1]) - j0_;              \
    int pos_ = __builtin_amdgcn_readfirstlane(sP[le_]);                      \
    float a0_ = 0.f, a1_ = 0.f;                                              \
    _Pragma("unroll")                                                        \
    for (int k_ = 0; k_ < 4; k_++)                                           \
      if (k_ < n_) {                                                         \
        a0_ += bf2f(ub[B][k_] & 0xffff);                                     \
        a1_ += bf2f(ub[B][k_] >> 16);                                        \
      }                                                                      \
    if (n_ > 4) {                                                            \
      for (int k_ = 4; k_ < n_; k_++) {                                      \
        int r_ = (k_ < 64) ? __builtin_amdgcn_readlane(idxv[I], k_)          \
                           : nme0[j0_ + k_];                                 \
        unsigned uu_ = xwu[(size_t)r_ * 64 + lane];                          \
        a0_ += bf2f(uu_ & 0xffff);                                           \
        a1_ += bf2f(uu_ >> 16);                                              \
      }                                                                      \
    }                                                                        \
    float m0_ = a0_ + bf2f(xs[I] & 0xffff) + bf2f(yy[I] & 0xffff);           \
    float m1_ = a1_ + bf2f(xs[I] >> 16) + bf2f(yy[I] >> 16);                 \
    unsigned um_ = ((unsigned)f2bf(m1_) << 16) | (unsigned)f2bf(m0_);        \
    __builtin_nontemporal_store(um_, &msgu[(size_t)pos_ * 64 + lane]);       \
    s0 += m0_; q0 += m0_ * m0_; s1 += m1_; q1 += m1_ * m1_;                  \
  } while (0)

__global__ __launch_bounds__(256, 8) void k_edge2(
    const unsigned* __restrict__ xwu, const int* __restrict__ nme0,
    const int* __restrict__ bnd,
    const unsigned* __restrict__ xslu, const unsigned* __restrict__ ylu,
    const int* __restrict__ dme0, const int* __restrict__ dme1,
    const int* __restrict__ inv,
    unsigned* __restrict__ msgu, float* __restrict__ part2) {
  __shared__ int sB[33], sD0[32], sD1[32], sP[32];
  __shared__ float sBN[1024];
  int tid = threadIdx.x, lane = tid & 63, wv = tid >> 6;
  int e0 = blockIdx.x * 32;
  if (tid < 33) sB[tid] = bnd[e0 + tid];
  else if (tid < 96 && tid >= 64) sD0[tid - 64] = dme0[e0 + tid - 64];
  else if (tid < 160 && tid >= 128) sD1[tid - 128] = dme1[e0 + tid - 128];
  else if (tid < 224 && tid >= 192) sP[tid - 192] = inv[e0 + tid - 192];
  __syncthreads();

  // Phase A: issue xs/yy/idxv for all 8 edges (24 independent loads in flight)
  unsigned xs[8], yy[8];
  int idxv[8];
#pragma unroll
  for (int i = 0; i < 8; i++) {
    int le = wv * 8 + i;
    int s = __builtin_amdgcn_readfirstlane(sD0[le]);
    int t = __builtin_amdgcn_readfirstlane(sD1[le]);
    int j0 = __builtin_amdgcn_readfirstlane(sB[le]);
    int n = __builtin_amdgcn_readfirstlane(sB[le + 1]) - j0;
    xs[i] = xslu[(size_t)s * 64 + lane];
    yy[i] = ylu[(size_t)t * 64 + lane];
    idxv[i] = (lane < n) ? nme0[j0 + lane] : 0;
  }

  float s0 = 0.f, q0 = 0.f, s1 = 0.f, q1 = 0.f;
  unsigned ub[3][4];
  EDGE_ISSUE(0, 0);
  EDGE_ISSUE(1, 1);
  EDGE_ISSUE(2, 2);
  EDGE_CONSUME(0, 0);
  EDGE_ISSUE(3, 0);
  EDGE_CONSUME(1, 1);
  EDGE_ISSUE(4, 1);
  EDGE_CONSUME(2, 2);
  EDGE_ISSUE(5, 2);
  EDGE_CONSUME(3, 0);
  EDGE_ISSUE(6, 0);
  EDGE_CONSUME(4, 1);
  EDGE_ISSUE(7, 1);
  EDGE_CONSUME(5, 2);
  EDGE_CONSUME(6, 0);
  EDGE_CONSUME(7, 1);

  *(float4*)(&sBN[wv * 256 + lane * 4]) = make_float4(s0, q0, s1, q1);
  __syncthreads();
  float v = sBN[tid] + sBN[256 + tid] + sBN[512 + tid] + sBN[768 + tid];
  atomicAdd(&part2[((blockIdx.x & 63) << 8) + tid], v);
}

// ---------------- BN stat finalize: sum the 64 spread slots + scale/shift
__global__ __launch_bounds__(256) void k_bnfinal(const float* __restrict__ part2,
                                                 const float* __restrict__ bnw,
                                                 const float* __restrict__ bnb,
                                                 float* __restrict__ ss) {
  __shared__ float L[256];
  float s = 0.f;
  for (int b = 0; b < 64; b++) s += part2[b * 256 + threadIdx.x];
  L[threadIdx.x] = s; __syncthreads();
  if (threadIdx.x < HH) {
    int c = threadIdx.x;
    float sum = L[2 * c], sq = L[2 * c + 1];
    float mean = sum / (float)cE_DOM;
    float var = sq / (float)cE_DOM - mean * mean;
    float sc = bnw[c] * rsqrtf(var + 1e-5f);
    float sh = bnb[c] - mean * sc;
    ss[2 * c] = sc; ss[2 * c + 1] = sh;
  }
}

// ---------------- final: msg is CSR-ordered, so each target reads a
// CONTIGUOUS run of rows [offs[t], offs[t+1]). 8-deep load batching.
__global__ __launch_bounds__(256, 8) void k_out2(const unsigned* __restrict__ msgu,
                                                 const int* __restrict__ offs,
                                                 const float* __restrict__ ss,
                                                 float* __restrict__ out) {
  int wv = threadIdx.x >> 6, lane = threadIdx.x & 63;
  int t = blockIdx.x * 4 + wv;
  if (t >= cN_Y) return;
  int c0 = lane * 2;
  float sc0 = ss[c0 * 2 + 0], sh0 = ss[c0 * 2 + 1];
  float sc1 = ss[c0 * 2 + 2], sh1 = ss[c0 * 2 + 3];
  int j0 = __builtin_amdgcn_readfirstlane(offs[t]);
  int j1 = __builtin_amdgcn_readfirstlane(offs[t + 1]);
  float a0 = 0.f, a1 = 0.f;
  int p = j0;
  for (; p + 8 <= j1; p += 8) {
    unsigned m[8];
#pragma unroll
    for (int k = 0; k < 8; k++) m[k] = msgu[(size_t)(p + k) * 64 + lane];
#pragma unroll
    for (int k = 0; k < 8; k++) {
      a0 += fmaxf(fmaf(bf2f(m[k] & 0xffff), sc0, sh0), 0.f);
      a1 += fmaxf(fmaf(bf2f(m[k] >> 16), sc1, sh1), 0.f);
    }
  }
  if (p + 4 <= j1) {
    unsigned m[4];
#pragma unroll
    for (int k = 0; k < 4; k++) m[k] = msgu[(size_t)(p + k) * 64 + lane];
#pragma unroll
    for (int k = 0; k < 4; k++) {
      a0 += fmaxf(fmaf(bf2f(m[k] & 0xffff), sc0, sh0), 0.f);
      a1 += fmaxf(fmaf(bf2f(m[k] >> 16), sc1, sh1), 0.f);
    }
    p += 4;
  }
  for (; p < j1; p++) {
    unsigned m = msgu[(size_t)p * 64 + lane];
    a0 += fmaxf(fmaf(bf2f(m & 0xffff), sc0, sh0), 0.f);
    a1 += fmaxf(fmaf(bf2f(m >> 16), sc1, sh1), 0.f);
  }
  *(float2*)(out + (size_t)t * HH + c0) = make_float2(a0, a1);
}

extern "C" void kernel_launch(void* const* d_in, const int* in_sizes, int n_in,
                              void* d_out, int out_size, void* d_ws, size_t ws_size,
                              hipStream_t stream) {
  const float* x     = (const float*)d_in[0];
  const float* y     = (const float*)d_in[1];
  const int* dom_ind = (const int*)d_in[2];
  const int* nme     = (const int*)d_in[3];
  const int* ii      = (const int*)d_in[4];
  const int* dme     = (const int*)d_in[5];
  const float* Wxsum = (const float*)d_in[6];
  const float* Wxint = (const float*)d_in[7];
  const float* Wy    = (const float*)d_in[8];
  const float* bnw   = (const float*)d_in[9];
  const float* bnb   = (const float*)d_in[10];
  float* out = (float*)d_out;

  char* ws = (char*)d_ws;
  size_t o = 0;
  auto alloc = [&](size_t bytes) -> void* {
    void* p = ws + o;
    o = (o + bytes + 255) & ~(size_t)255;
    return p;
  };
  float* xsum   = (float*)alloc((size_t)cN_SRC * HH * 4);
  unsigned short* xsl = (unsigned short*)alloc((size_t)cN_SRC * HH * 2);
  unsigned short* ylin = (unsigned short*)alloc((size_t)cN_Y * HH * 2);
  unsigned short* xw = (unsigned short*)alloc((size_t)cN_X * HH * 2);
  unsigned short* msg = (unsigned short*)alloc((size_t)cE_DOM * HH * 2);
  int* bnd      = (int*)alloc((size_t)(cN_INT + 1) * 4);
  int* cnt      = (int*)alloc((size_t)cN_SRC * 4);
  int* excl     = (int*)alloc((size_t)cN_SRC * 4);
  int* bsum     = (int*)alloc(256 * 4);
  int* offs     = (int*)alloc((size_t)(cN_SRC + 1) * 4);
  int* cursor   = (int*)alloc((size_t)cN_SRC * 4);
  int* inv      = (int*)alloc((size_t)cE_DOM * 4);
  float* part2  = (float*)alloc(64 * 256 * 4);
  float* ssbuf  = (float*)alloc(256 * 4);
  unsigned short* Wbf = (unsigned short*)alloc(3 * 16384 * 2);

  hipMemsetAsync(xsum, 0, (size_t)cN_SRC * HH * 4, stream);
  hipMemsetAsync(cnt, 0, (size_t)cN_SRC * 4, stream);
  hipMemsetAsync(part2, 0, 64 * 256 * 4, stream);

  k_wcast<<<48, 256, 0, stream>>>(Wxsum, Wy, Wxint, Wbf);
  k_segsum_x<<<(cN_X + 127) / 128, 256, 0, stream>>>(x, dom_ind, xsum);
  k_gemm128b<<<(cN_X + 63) / 64, 256, 0, stream>>>(x, Wbf + 32768, xw, cN_X);
  k_gemm128b<<<(cN_SRC + 63) / 64, 256, 0, stream>>>(xsum, Wbf, xsl, cN_SRC);
  k_gemm128b<<<(cN_Y + 63) / 64, 256, 0, stream>>>(y, Wbf + 16384, ylin, cN_Y);
  k_bounds<<<(cE_NODE + 1 + 255) / 256, 256, 0, stream>>>(ii, bnd);
  k_hist<<<(cE_DOM + 255) / 256, 256, 0, stream>>>(dme + cE_DOM, cnt);
  k_scan1<<<(cN_SRC + 255) / 256, 256, 0, stream>>>(cnt, bsum, excl);
  k_scan2<<<1, 256, 0, stream>>>(bsum, (cN_SRC + 255) / 256);
  k_scan3<<<(cN_SRC + 1 + 255) / 256, 256, 0, stream>>>(excl, bsum, offs, cursor);
  k_scatter<<<(cE_DOM + 255) / 256, 256, 0, stream>>>(dme + cE_DOM, cursor, inv);
  k_edge2<<<cE_DOM / 32, 256, 0, stream>>>((const unsigned*)xw, nme, bnd,
                                           (const unsigned*)xsl, (const unsigned*)ylin,
                                           dme, dme + cE_DOM, inv,
                                           (unsigned*)msg, part2);
  k_bnfinal<<<1, 256, 0, stream>>>(part2, bnw, bnb, ssbuf);
  k_out2<<<(cN_Y + 3) / 4, 256, 0, stream>>>((const unsigned*)msg, offs, ssbuf, out);
}

// Round 3
// 465.736 us; speedup vs baseline: 1.3656x; 1.0273x over previous
//
#include <hip/hip_runtime.h>
#include <cstdint>

#define HH 128
#define SB 136  // padded bf16 LDS row stride for GEMM A tiles (272 B: 16B-aligned, 2-way max bank alias)
constexpr int cN_X   = 250000;
constexpr int cN_SRC = 50000;
constexpr int cN_Y   = 50000;
constexpr int cN_INT = 500000;
constexpr int cE_NODE = 1000000;
constexpr int cE_DOM  = 500000;

typedef __attribute__((ext_vector_type(8))) short bf16x8;
typedef __attribute__((ext_vector_type(4))) float f32x4;

__device__ __forceinline__ float bf2f(unsigned short s) {
  union { unsigned u; float f; } v; v.u = ((unsigned)s) << 16; return v.f;
}
__device__ __forceinline__ unsigned short f2bf(float f) {
  union { float f; unsigned u; } v; v.f = f;
  unsigned r = v.u + 0x7fffu + ((v.u >> 16) & 1u);  // RNE
  return (unsigned short)(r >> 16);
}

// ---------------- cast the three W matrices to bf16 (row-major) once
__global__ __launch_bounds__(256) void k_wcast(const float* __restrict__ w0,
                                               const float* __restrict__ w1,
                                               const float* __restrict__ w2,
                                               unsigned short* __restrict__ dst) {
  int i = blockIdx.x * 256 + threadIdx.x;
  int idx4 = i * 4;
  int mat = idx4 >> 14;
  int off = idx4 & 16383;
  const float* src = (mat == 0) ? w0 : (mat == 1) ? w1 : w2;
  float4 v = *(const float4*)(src + off);
  ushort4 u;
  u.x = f2bf(v.x); u.y = f2bf(v.y); u.z = f2bf(v.z); u.w = f2bf(v.w);
  *(ushort4*)(dst + (size_t)mat * 16384 + off) = u;
}

// ---------------- MFMA helpers
__device__ __forceinline__ void load_bfrags(const unsigned short* __restrict__ Wbf,
                                            int wv, int lane, bf16x8 bfrag[2][4]) {
  int cbase = wv * 32 + (lane & 15);
  int krow = (lane >> 4) * 8;
#pragma unroll
  for (int ct = 0; ct < 2; ct++)
#pragma unroll
    for (int kt = 0; kt < 4; kt++)
      bfrag[ct][kt] = *(const bf16x8*)(Wbf + (size_t)(cbase + ct * 16) * HH + kt * 32 + krow);
}

// ---------------- fused: xw[M][128](bf16) = x @ Wxint^T  AND  xsum += segsum(x)
// Both consume all of x; the segsum side re-reads the block's rows right after
// staging, so those hit L1/L2, not HBM. Segsum math identical to the old
// standalone kernel (f32 adds of f32 loads, atomics only at chunk boundaries).
__global__ __launch_bounds__(256, 4) void k_gemmx_segsum(
    const float* __restrict__ A, const int* __restrict__ ind,
    const unsigned short* __restrict__ Wbf,
    unsigned short* __restrict__ outb, float* __restrict__ xsum) {
  __shared__ unsigned short sA[64 * SB];
  __shared__ int sind[64];
  int tid = threadIdx.x, lane = tid & 63, wv = tid >> 6;
  int row0 = blockIdx.x * 64;
  int rows = min(64, cN_X - row0);
  if (tid < 64 && tid < rows) sind[tid] = ind[row0 + tid];
  bf16x8 bfrag[2][4];
  load_bfrags(Wbf, wv, lane, bfrag);
  // stage 64x128 f32 -> bf16 LDS
#pragma unroll
  for (int it = 0; it < 4; it++) {
    int g = it * 2048 + tid * 8;
    int r = g >> 7, c = g & 127;
    bf16x8 v = {0, 0, 0, 0, 0, 0, 0, 0};
    if (r < rows) {
      float4 f0 = *(const float4*)(A + (size_t)(row0 + r) * HH + c);
      float4 f1 = *(const float4*)(A + (size_t)(row0 + r) * HH + c + 4);
      v[0] = (short)f2bf(f0.x); v[1] = (short)f2bf(f0.y);
      v[2] = (short)f2bf(f0.z); v[3] = (short)f2bf(f0.w);
      v[4] = (short)f2bf(f1.x); v[5] = (short)f2bf(f1.y);
      v[6] = (short)f2bf(f1.z); v[7] = (short)f2bf(f1.w);
    }
    *(bf16x8*)(&sA[r * SB + c]) = v;
  }
  __syncthreads();
  // ---- segment-sum side: wave wv owns rows [wv*16, wv*16+16), lane = col pair
  {
    int rbase = wv * 16;
    if (rbase < rows) {
      int nr = min(16, rows - rbase);
      int c0 = lane * 2;
      float a0 = 0.f, a1 = 0.f;
      int cur = sind[rbase];
      bool inside = false;
      for (int r0 = 0; r0 < nr; r0 += 8) {
        int nb = min(8, nr - r0);
        float2 v[8];
#pragma unroll
        for (int k = 0; k < 8; k++)
          if (k < nb) v[k] = *(const float2*)(A + (size_t)(row0 + rbase + r0 + k) * HH + c0);
#pragma unroll
        for (int k = 0; k < 8; k++) {
          if (k < nb) {
            int s = sind[rbase + r0 + k];
            if (s != cur) {
              if (inside) {
                xsum[(size_t)cur * HH + c0] = a0;
                xsum[(size_t)cur * HH + c0 + 1] = a1;
              } else {
                atomicAdd(&xsum[(size_t)cur * HH + c0], a0);
                atomicAdd(&xsum[(size_t)cur * HH + c0 + 1], a1);
              }
              cur = s; a0 = 0.f; a1 = 0.f; inside = true;
            }
            a0 += v[k].x; a1 += v[k].y;
          }
        }
      }
      atomicAdd(&xsum[(size_t)cur * HH + c0], a0);
      atomicAdd(&xsum[(size_t)cur * HH + c0 + 1], a1);
    }
  }
  // ---- MFMA side
  int m = lane & 15, q = lane >> 4;
  f32x4 acc[4][2];
#pragma unroll
  for (int rt = 0; rt < 4; rt++)
#pragma unroll
    for (int ct = 0; ct < 2; ct++) acc[rt][ct] = (f32x4){0.f, 0.f, 0.f, 0.f};
#pragma unroll
  for (int kt = 0; kt < 4; kt++) {
    int kof = kt * 32 + q * 8;
#pragma unroll
    for (int rt = 0; rt < 4; rt++) {
      bf16x8 af = *(const bf16x8*)(&sA[(rt * 16 + m) * SB + kof]);
      acc[rt][0] = __builtin_amdgcn_mfma_f32_16x16x32_bf16(af, bfrag[0][kt], acc[rt][0], 0, 0, 0);
      acc[rt][1] = __builtin_amdgcn_mfma_f32_16x16x32_bf16(af, bfrag[1][kt], acc[rt][1], 0, 0, 0);
    }
  }
  __syncthreads();
  unsigned short* sC = sA;
#pragma unroll
  for (int rt = 0; rt < 4; rt++)
#pragma unroll
    for (int ct = 0; ct < 2; ct++)
#pragma unroll
      for (int rg = 0; rg < 4; rg++) {
        int r = rt * 16 + q * 4 + rg;
        sC[r * HH + wv * 32 + ct * 16 + m] = f2bf(acc[rt][ct][rg]);
      }
  __syncthreads();
  for (int i = tid; i < rows * 16; i += 256) {
    int r = i >> 4, g = i & 15;
    ((uint4*)(outb + (size_t)(row0 + r) * HH))[g] = ((const uint4*)(sC + r * HH))[g];
  }
}

// ---------------- outb[M][128] (bf16) = A[M][128] @ W^T via MFMA (xsum, y)
__global__ __launch_bounds__(256, 4) void k_gemm128b(const float* __restrict__ A,
                                                     const unsigned short* __restrict__ Wbf,
                                                     unsigned short* __restrict__ outb, int M) {
  __shared__ unsigned short sA[64 * SB];
  int tid = threadIdx.x, lane = tid & 63, wv = tid >> 6;
  int row0 = blockIdx.x * 64;
  int rows = min(64, M - row0);
  bf16x8 bfrag[2][4];
  load_bfrags(Wbf, wv, lane, bfrag);
#pragma unroll
  for (int it = 0; it < 4; it++) {
    int g = it * 2048 + tid * 8;
    int r = g >> 7, c = g & 127;
    bf16x8 v = {0, 0, 0, 0, 0, 0, 0, 0};
    if (r < rows) {
      float4 f0 = *(const float4*)(A + (size_t)(row0 + r) * HH + c);
      float4 f1 = *(const float4*)(A + (size_t)(row0 + r) * HH + c + 4);
      v[0] = (short)f2bf(f0.x); v[1] = (short)f2bf(f0.y);
      v[2] = (short)f2bf(f0.z); v[3] = (short)f2bf(f0.w);
      v[4] = (short)f2bf(f1.x); v[5] = (short)f2bf(f1.y);
      v[6] = (short)f2bf(f1.z); v[7] = (short)f2bf(f1.w);
    }
    *(bf16x8*)(&sA[r * SB + c]) = v;
  }
  __syncthreads();
  int m = lane & 15, q = lane >> 4;
  f32x4 acc[4][2];
#pragma unroll
  for (int rt = 0; rt < 4; rt++)
#pragma unroll
    for (int ct = 0; ct < 2; ct++) acc[rt][ct] = (f32x4){0.f, 0.f, 0.f, 0.f};
#pragma unroll
  for (int kt = 0; kt < 4; kt++) {
    int kof = kt * 32 + q * 8;
#pragma unroll
    for (int rt = 0; rt < 4; rt++) {
      bf16x8 af = *(const bf16x8*)(&sA[(rt * 16 + m) * SB + kof]);
      acc[rt][0] = __builtin_amdgcn_mfma_f32_16x16x32_bf16(af, bfrag[0][kt], acc[rt][0], 0, 0, 0);
      acc[rt][1] = __builtin_amdgcn_mfma_f32_16x16x32_bf16(af, bfrag[1][kt], acc[rt][1], 0, 0, 0);
    }
  }
  __syncthreads();
  unsigned short* sC = sA;
#pragma unroll
  for (int rt = 0; rt < 4; rt++)
#pragma unroll
    for (int ct = 0; ct < 2; ct++)
#pragma unroll
      for (int rg = 0; rg < 4; rg++) {
        int r = rt * 16 + q * 4 + rg;
        sC[r * HH + wv * 32 + ct * 16 + m] = f2bf(acc[rt][ct][rg]);
      }
  __syncthreads();
  for (int i = tid; i < rows * 16; i += 256) {
    int r = i >> 4, g = i & 15;
    ((uint4*)(outb + (size_t)(row0 + r) * HH))[g] = ((const uint4*)(sC + r * HH))[g];
  }
}

// ---------------- bnd via linear boundary marking + dme1 histogram (fused)
__global__ __launch_bounds__(256) void k_bounds_hist(const int* __restrict__ ii,
                                                     int* __restrict__ bnd,
                                                     const int* __restrict__ dme1,
                                                     int* __restrict__ cnt) {
  int j = blockIdx.x * 256 + threadIdx.x;
  if (j < cE_DOM) atomicAdd(&cnt[dme1[j]], 1);
  if (j > cE_NODE) return;
  if (j == cE_NODE) {
    int a = ii[cE_NODE - 1];
    for (int e = a + 1; e <= cN_INT; ++e) bnd[e] = cE_NODE;
    return;
  }
  int b = ii[j];
  int a = (j == 0) ? -1 : ii[j - 1];
  for (int e = a + 1; e <= b; ++e) bnd[e] = j;
}

// ---------------- CSR build: offs + per-position records {s, t, j0, n}
__global__ __launch_bounds__(256) void k_scan1(const int* __restrict__ cnt,
                                               int* __restrict__ bsum, int* __restrict__ excl) {
  __shared__ int buf[256];
  int i = blockIdx.x * 256 + threadIdx.x;
  int v = (i < cN_SRC) ? cnt[i] : 0;
  buf[threadIdx.x] = v; __syncthreads();
  for (int d = 1; d < 256; d <<= 1) {
    int t = (threadIdx.x >= d) ? buf[threadIdx.x - d] : 0;
    __syncthreads();
    buf[threadIdx.x] += t;
    __syncthreads();
  }
  if (i < cN_SRC) excl[i] = buf[threadIdx.x] - v;
  if (threadIdx.x == 255) bsum[blockIdx.x] = buf[255];
}
__global__ __launch_bounds__(256) void k_scan2(int* __restrict__ bsum, int nb) {
  __shared__ int buf[256];
  int v = (threadIdx.x < nb) ? bsum[threadIdx.x] : 0;
  buf[threadIdx.x] = v; __syncthreads();
  for (int d = 1; d < 256; d <<= 1) {
    int t = (threadIdx.x >= d) ? buf[threadIdx.x - d] : 0;
    __syncthreads();
    buf[threadIdx.x] += t;
    __syncthreads();
  }
  if (threadIdx.x < nb) bsum[threadIdx.x] = buf[threadIdx.x] - v;
}
__global__ void k_scan3(const int* __restrict__ excl, const int* __restrict__ bsum,
                        int* __restrict__ offs, int* __restrict__ cursor) {
  int i = blockIdx.x * 256 + threadIdx.x;
  if (i < cN_SRC) { int o = excl[i] + bsum[i >> 8]; offs[i] = o; cursor[i] = o; }
  else if (i == cN_SRC) offs[cN_SRC] = cE_DOM;
}
// scatter: pre-gather ALL per-edge metadata into CSR position order while the
// e-indexed reads are still coalesced. rec[pos] = {s=dme0[e], t=dme1[e],
// j0=bnd[e], n=bnd[e+1]-bnd[e]}.
__global__ void k_scatter(const int* __restrict__ dme0, const int* __restrict__ dme1,
                          const int* __restrict__ bnd, int* __restrict__ cursor,
                          int4* __restrict__ rec) {
  int e = blockIdx.x * blockDim.x + threadIdx.x;
  if (e < cE_DOM) {
    int t = dme1[e];
    int pos = atomicAdd(&cursor[t], 1);
    int j0 = bnd[e];
    rec[pos] = make_int4(dme0[e], t, j0, bnd[e + 1] - j0);
  }
}

// ---------------- edge kernel v5: CSR-position order, wave-per-edge (8/wave).
// All metadata from one coalesced int4 read; msg writes perfectly sequential
// (pos = e0+le is compile-time offset from block base); ylu[t] reads come in
// runs of equal t (L1 hits). Batch phase-A loads + depth-2 gather pipeline.
#define EDGE_ISSUE(I, B)                                                     \
  do {                                                                       \
    int le_ = wv * 8 + (I);                                                  \
    int n_ = __builtin_amdgcn_readfirstlane(sR[le_].w);                      \
    _Pragma("unroll")                                                        \
    for (int k_ = 0; k_ < 4; k_++)                                           \
      if (k_ < n_) {                                                         \
        int r_ = __builtin_amdgcn_readlane(idxv[I], k_);                     \
        ub[B][k_] = xwu[(size_t)r_ * 64 + lane];                             \
      }                                                                      \
  } while (0)

#define EDGE_CONSUME(I, B)                                                   \
  do {                                                                       \
    int le_ = wv * 8 + (I);                                                  \
    int j0_ = __builtin_amdgcn_readfirstlane(sR[le_].z);                     \
    int n_ = __builtin_amdgcn_readfirstlane(sR[le_].w);                      \
    float a0_ = 0.f, a1_ = 0.f;                                              \
    _Pragma("unroll")                                                        \
    for (int k_ = 0; k_ < 4; k_++)                                           \
      if (k_ < n_) {                                                         \
        a0_ += bf2f(ub[B][k_] & 0xffff);                                     \
        a1_ += bf2f(ub[B][k_] >> 16);                                        \
      }                                                                      \
    if (n_ > 4) {                                                            \
      for (int k_ = 4; k_ < n_; k_++) {                                      \
        int r_ = (k_ < 64) ? __builtin_amdgcn_readlane(idxv[I], k_)          \
                           : nme0[j0_ + k_];                                 \
        unsigned uu_ = xwu[(size_t)r_ * 64 + lane];                          \
        a0_ += bf2f(uu_ & 0xffff);                                           \
        a1_ += bf2f(uu_ >> 16);                                              \
      }                                                                      \
    }                                                                        \
    float m0_ = a0_ + bf2f(xs[I] & 0xffff) + bf2f(yy[I] & 0xffff);           \
    float m1_ = a1_ + bf2f(xs[I] >> 16) + bf2f(yy[I] >> 16);                 \
    unsigned um_ = ((unsigned)f2bf(m1_) << 16) | (unsigned)f2bf(m0_);        \
    __builtin_nontemporal_store(um_, &msgu[(size_t)(e0 + le_) * 64 + lane]); \
    s0 += m0_; q0 += m0_ * m0_; s1 += m1_; q1 += m1_ * m1_;                  \
  } while (0)

__global__ __launch_bounds__(256, 8) void k_edge2(
    const unsigned* __restrict__ xwu, const int* __restrict__ nme0,
    const unsigned* __restrict__ xslu, const unsigned* __restrict__ ylu,
    const int4* __restrict__ rec,
    unsigned* __restrict__ msgu, float* __restrict__ part2) {
  __shared__ int4 sR[32];
  __shared__ float sBN[1024];
  int tid = threadIdx.x, lane = tid & 63, wv = tid >> 6;
  int e0 = blockIdx.x * 32;
  if (tid < 32) sR[tid] = rec[e0 + tid];
  __syncthreads();

  // Phase A: issue xs/yy/idxv for all 8 edges (24 independent loads in flight)
  unsigned xs[8], yy[8];
  int idxv[8];
#pragma unroll
  for (int i = 0; i < 8; i++) {
    int le = wv * 8 + i;
    int s  = __builtin_amdgcn_readfirstlane(sR[le].x);
    int t  = __builtin_amdgcn_readfirstlane(sR[le].y);
    int j0 = __builtin_amdgcn_readfirstlane(sR[le].z);
    int n  = __builtin_amdgcn_readfirstlane(sR[le].w);
    xs[i] = xslu[(size_t)s * 64 + lane];
    yy[i] = ylu[(size_t)t * 64 + lane];
    idxv[i] = (lane < n) ? nme0[j0 + lane] : 0;
  }

  float s0 = 0.f, q0 = 0.f, s1 = 0.f, q1 = 0.f;
  unsigned ub[3][4];
  EDGE_ISSUE(0, 0);
  EDGE_ISSUE(1, 1);
  EDGE_ISSUE(2, 2);
  EDGE_CONSUME(0, 0);
  EDGE_ISSUE(3, 0);
  EDGE_CONSUME(1, 1);
  EDGE_ISSUE(4, 1);
  EDGE_CONSUME(2, 2);
  EDGE_ISSUE(5, 2);
  EDGE_CONSUME(3, 0);
  EDGE_ISSUE(6, 0);
  EDGE_CONSUME(4, 1);
  EDGE_ISSUE(7, 1);
  EDGE_CONSUME(5, 2);
  EDGE_CONSUME(6, 0);
  EDGE_CONSUME(7, 1);

  *(float4*)(&sBN[wv * 256 + lane * 4]) = make_float4(s0, q0, s1, q1);
  __syncthreads();
  float v = sBN[tid] + sBN[256 + tid] + sBN[512 + tid] + sBN[768 + tid];
  atomicAdd(&part2[((blockIdx.x & 63) << 8) + tid], v);
}

// ---------------- BN stat finalize: sum the 64 spread slots + scale/shift
__global__ __launch_bounds__(256) void k_bnfinal(const float* __restrict__ part2,
                                                 const float* __restrict__ bnw,
                                                 const float* __restrict__ bnb,
                                                 float* __restrict__ ss) {
  __shared__ float L[256];
  float s = 0.f;
  for (int b = 0; b < 64; b++) s += part2[b * 256 + threadIdx.x];
  L[threadIdx.x] = s; __syncthreads();
  if (threadIdx.x < HH) {
    int c = threadIdx.x;
    float sum = L[2 * c], sq = L[2 * c + 1];
    float mean = sum / (float)cE_DOM;
    float var = sq / (float)cE_DOM - mean * mean;
    float sc = bnw[c] * rsqrtf(var + 1e-5f);
    float sh = bnb[c] - mean * sc;
    ss[2 * c] = sc; ss[2 * c + 1] = sh;
  }
}

// ---------------- final: msg is CSR-ordered, so each target reads a
// CONTIGUOUS run of rows [offs[t], offs[t+1]). 8-deep load batching.
__global__ __launch_bounds__(256, 8) void k_out2(const unsigned* __restrict__ msgu,
                                                 const int* __restrict__ offs,
                                                 const float* __restrict__ ss,
                                                 float* __restrict__ out) {
  int wv = threadIdx.x >> 6, lane = threadIdx.x & 63;
  int t = blockIdx.x * 4 + wv;
  if (t >= cN_Y) return;
  int c0 = lane * 2;
  float sc0 = ss[c0 * 2 + 0], sh0 = ss[c0 * 2 + 1];
  float sc1 = ss[c0 * 2 + 2], sh1 = ss[c0 * 2 + 3];
  int j0 = __builtin_amdgcn_readfirstlane(offs[t]);
  int j1 = __builtin_amdgcn_readfirstlane(offs[t + 1]);
  float a0 = 0.f, a1 = 0.f;
  int p = j0;
  for (; p + 8 <= j1; p += 8) {
    unsigned m[8];
#pragma unroll
    for (int k = 0; k < 8; k++) m[k] = msgu[(size_t)(p + k) * 64 + lane];
#pragma unroll
    for (int k = 0; k < 8; k++) {
      a0 += fmaxf(fmaf(bf2f(m[k] & 0xffff), sc0, sh0), 0.f);
      a1 += fmaxf(fmaf(bf2f(m[k] >> 16), sc1, sh1), 0.f);
    }
  }
  if (p + 4 <= j1) {
    unsigned m[4];
#pragma unroll
    for (int k = 0; k < 4; k++) m[k] = msgu[(size_t)(p + k) * 64 + lane];
#pragma unroll
    for (int k = 0; k < 4; k++) {
      a0 += fmaxf(fmaf(bf2f(m[k] & 0xffff), sc0, sh0), 0.f);
      a1 += fmaxf(fmaf(bf2f(m[k] >> 16), sc1, sh1), 0.f);
    }
    p += 4;
  }
  for (; p < j1; p++) {
    unsigned m = msgu[(size_t)p * 64 + lane];
    a0 += fmaxf(fmaf(bf2f(m & 0xffff), sc0, sh0), 0.f);
    a1 += fmaxf(fmaf(bf2f(m >> 16), sc1, sh1), 0.f);
  }
  *(float2*)(out + (size_t)t * HH + c0) = make_float2(a0, a1);
}

extern "C" void kernel_launch(void* const* d_in, const int* in_sizes, int n_in,
                              void* d_out, int out_size, void* d_ws, size_t ws_size,
                              hipStream_t stream) {
  const float* x     = (const float*)d_in[0];
  const float* y     = (const float*)d_in[1];
  const int* dom_ind = (const int*)d_in[2];
  const int* nme     = (const int*)d_in[3];
  const int* ii      = (const int*)d_in[4];
  const int* dme     = (const int*)d_in[5];
  const float* Wxsum = (const float*)d_in[6];
  const float* Wxint = (const float*)d_in[7];
  const float* Wy    = (const float*)d_in[8];
  const float* bnw   = (const float*)d_in[9];
  const float* bnb   = (const float*)d_in[10];
  float* out = (float*)d_out;

  char* ws = (char*)d_ws;
  size_t o = 0;
  auto alloc = [&](size_t bytes) -> void* {
    void* p = ws + o;
    o = (o + bytes + 255) & ~(size_t)255;
    return p;
  };
  float* xsum   = (float*)alloc((size_t)cN_SRC * HH * 4);
  unsigned short* xsl = (unsigned short*)alloc((size_t)cN_SRC * HH * 2);
  unsigned short* ylin = (unsigned short*)alloc((size_t)cN_Y * HH * 2);
  unsigned short* xw = (unsigned short*)alloc((size_t)cN_X * HH * 2);
  unsigned short* msg = (unsigned short*)alloc((size_t)cE_DOM * HH * 2);
  int* bnd      = (int*)alloc((size_t)(cN_INT + 1) * 4);
  int* cnt      = (int*)alloc((size_t)cN_SRC * 4);
  int* excl     = (int*)alloc((size_t)cN_SRC * 4);
  int* bsum     = (int*)alloc(256 * 4);
  int* offs     = (int*)alloc((size_t)(cN_SRC + 1) * 4);
  int* cursor   = (int*)alloc((size_t)cN_SRC * 4);
  int4* rec     = (int4*)alloc((size_t)cE_DOM * 16);
  float* part2  = (float*)alloc(64 * 256 * 4);
  float* ssbuf  = (float*)alloc(256 * 4);
  unsigned short* Wbf = (unsigned short*)alloc(3 * 16384 * 2);

  hipMemsetAsync(xsum, 0, (size_t)cN_SRC * HH * 4, stream);
  hipMemsetAsync(cnt, 0, (size_t)cN_SRC * 4, stream);
  hipMemsetAsync(part2, 0, 64 * 256 * 4, stream);

  k_wcast<<<48, 256, 0, stream>>>(Wxsum, Wy, Wxint, Wbf);
  k_gemmx_segsum<<<(cN_X + 63) / 64, 256, 0, stream>>>(x, dom_ind, Wbf + 32768, xw, xsum);
  k_gemm128b<<<(cN_SRC + 63) / 64, 256, 0, stream>>>(xsum, Wbf, xsl, cN_SRC);
  k_gemm128b<<<(cN_Y + 63) / 64, 256, 0, stream>>>(y, Wbf + 16384, ylin, cN_Y);
  k_bounds_hist<<<(cE_NODE + 1 + 255) / 256, 256, 0, stream>>>(ii, bnd, dme + cE_DOM, cnt);
  k_scan1<<<(cN_SRC + 255) / 256, 256, 0, stream>>>(cnt, bsum, excl);
  k_scan2<<<1, 256, 0, stream>>>(bsum, (cN_SRC + 255) / 256);
  k_scan3<<<(cN_SRC + 1 + 255) / 256, 256, 0, stream>>>(excl, bsum, offs, cursor);
  k_scatter<<<(cE_DOM + 255) / 256, 256, 0, stream>>>(dme, dme + cE_DOM, bnd, cursor, rec);
  k_edge2<<<cE_DOM / 32, 256, 0, stream>>>((const unsigned*)xw, nme,
                                           (const unsigned*)xsl, (const unsigned*)ylin,
                                           rec, (unsigned*)msg, part2);
  k_bnfinal<<<1, 256, 0, stream>>>(part2, bnw, bnb, ssbuf);
  k_out2<<<(cN_Y + 3) / 4, 256, 0, stream>>>((const unsigned*)msg, offs, ssbuf, out);
}

// Round 4
// 448.487 us; speedup vs baseline: 1.4182x; 1.0385x over previous
//
#include <hip/hip_runtime.h>
#include <cstdint>

#define HH 128
#define SB 136  // padded bf16 LDS row stride for GEMM A tiles (272 B: 16B-aligned, 2-way max bank alias)
constexpr int cN_X   = 250000;
constexpr int cN_SRC = 50000;
constexpr int cN_Y   = 50000;
constexpr int cN_INT = 500000;
constexpr int cE_NODE = 1000000;
constexpr int cE_DOM  = 500000;

typedef __attribute__((ext_vector_type(8))) short bf16x8;
typedef __attribute__((ext_vector_type(4))) float f32x4;

__device__ __forceinline__ float bf2f(unsigned short s) {
  union { unsigned u; float f; } v; v.u = ((unsigned)s) << 16; return v.f;
}
__device__ __forceinline__ unsigned short f2bf(float f) {
  union { float f; unsigned u; } v; v.f = f;
  unsigned r = v.u + 0x7fffu + ((v.u >> 16) & 1u);  // RNE
  return (unsigned short)(r >> 16);
}

// ---------------- cast the three W matrices to bf16 (row-major) once
__global__ __launch_bounds__(256) void k_wcast(const float* __restrict__ w0,
                                               const float* __restrict__ w1,
                                               const float* __restrict__ w2,
                                               unsigned short* __restrict__ dst) {
  int i = blockIdx.x * 256 + threadIdx.x;
  int idx4 = i * 4;
  int mat = idx4 >> 14;
  int off = idx4 & 16383;
  const float* src = (mat == 0) ? w0 : (mat == 1) ? w1 : w2;
  float4 v = *(const float4*)(src + off);
  ushort4 u;
  u.x = f2bf(v.x); u.y = f2bf(v.y); u.z = f2bf(v.z); u.w = f2bf(v.w);
  *(ushort4*)(dst + (size_t)mat * 16384 + off) = u;
}

// ---------------- MFMA helpers
__device__ __forceinline__ void load_bfrags(const unsigned short* __restrict__ Wbf,
                                            int wv, int lane, bf16x8 bfrag[2][4]) {
  int cbase = wv * 32 + (lane & 15);
  int krow = (lane >> 4) * 8;
#pragma unroll
  for (int ct = 0; ct < 2; ct++)
#pragma unroll
    for (int kt = 0; kt < 4; kt++)
      bfrag[ct][kt] = *(const bf16x8*)(Wbf + (size_t)(cbase + ct * 16) * HH + kt * 32 + krow);
}

// ---------------- fused: xw[M][128](bf16) = x @ Wxint^T  AND  xsum += segsum(x)
// Segsum side now reads the STAGED bf16 LDS tile (no second global pass over x).
// Accumulation stays f32; inputs are bf16-rounded (adds ~1e-2 abs error into
// xsum, negligible vs the pipeline's existing bf16 rounding).
__global__ __launch_bounds__(256, 4) void k_gemmx_segsum(
    const float* __restrict__ A, const int* __restrict__ ind,
    const unsigned short* __restrict__ Wbf,
    unsigned short* __restrict__ outb, float* __restrict__ xsum) {
  __shared__ unsigned short sA[64 * SB];
  __shared__ int sind[64];
  int tid = threadIdx.x, lane = tid & 63, wv = tid >> 6;
  int row0 = blockIdx.x * 64;
  int rows = min(64, cN_X - row0);
  if (tid < 64 && tid < rows) sind[tid] = ind[row0 + tid];
  bf16x8 bfrag[2][4];
  load_bfrags(Wbf, wv, lane, bfrag);
  // stage 64x128 f32 -> bf16 LDS
#pragma unroll
  for (int it = 0; it < 4; it++) {
    int g = it * 2048 + tid * 8;
    int r = g >> 7, c = g & 127;
    bf16x8 v = {0, 0, 0, 0, 0, 0, 0, 0};
    if (r < rows) {
      float4 f0 = *(const float4*)(A + (size_t)(row0 + r) * HH + c);
      float4 f1 = *(const float4*)(A + (size_t)(row0 + r) * HH + c + 4);
      v[0] = (short)f2bf(f0.x); v[1] = (short)f2bf(f0.y);
      v[2] = (short)f2bf(f0.z); v[3] = (short)f2bf(f0.w);
      v[4] = (short)f2bf(f1.x); v[5] = (short)f2bf(f1.y);
      v[6] = (short)f2bf(f1.z); v[7] = (short)f2bf(f1.w);
    }
    *(bf16x8*)(&sA[r * SB + c]) = v;
  }
  __syncthreads();
  // ---- segment-sum side: wave wv owns rows [wv*16, wv*16+16), lane = col pair.
  // Reads the LDS bf16 tile (L1-free, no global traffic).
  {
    int rbase = wv * 16;
    if (rbase < rows) {
      int nr = min(16, rows - rbase);
      int c0 = lane * 2;
      unsigned xv[16];
#pragma unroll
      for (int k = 0; k < 16; k++)
        xv[k] = (k < nr) ? *(const unsigned*)(&sA[(rbase + k) * SB + c0]) : 0u;
      float a0 = 0.f, a1 = 0.f;
      int cur = sind[rbase];
      bool inside = false;
#pragma unroll
      for (int k = 0; k < 16; k++) {
        if (k < nr) {
          int s = sind[rbase + k];
          if (s != cur) {
            if (inside) {
              xsum[(size_t)cur * HH + c0] = a0;
              xsum[(size_t)cur * HH + c0 + 1] = a1;
            } else {
              atomicAdd(&xsum[(size_t)cur * HH + c0], a0);
              atomicAdd(&xsum[(size_t)cur * HH + c0 + 1], a1);
            }
            cur = s; a0 = 0.f; a1 = 0.f; inside = true;
          }
          a0 += bf2f(xv[k] & 0xffff); a1 += bf2f(xv[k] >> 16);
        }
      }
      atomicAdd(&xsum[(size_t)cur * HH + c0], a0);
      atomicAdd(&xsum[(size_t)cur * HH + c0 + 1], a1);
    }
  }
  // ---- MFMA side
  int m = lane & 15, q = lane >> 4;
  f32x4 acc[4][2];
#pragma unroll
  for (int rt = 0; rt < 4; rt++)
#pragma unroll
    for (int ct = 0; ct < 2; ct++) acc[rt][ct] = (f32x4){0.f, 0.f, 0.f, 0.f};
#pragma unroll
  for (int kt = 0; kt < 4; kt++) {
    int kof = kt * 32 + q * 8;
#pragma unroll
    for (int rt = 0; rt < 4; rt++) {
      bf16x8 af = *(const bf16x8*)(&sA[(rt * 16 + m) * SB + kof]);
      acc[rt][0] = __builtin_amdgcn_mfma_f32_16x16x32_bf16(af, bfrag[0][kt], acc[rt][0], 0, 0, 0);
      acc[rt][1] = __builtin_amdgcn_mfma_f32_16x16x32_bf16(af, bfrag[1][kt], acc[rt][1], 0, 0, 0);
    }
  }
  __syncthreads();
  unsigned short* sC = sA;
#pragma unroll
  for (int rt = 0; rt < 4; rt++)
#pragma unroll
    for (int ct = 0; ct < 2; ct++)
#pragma unroll
      for (int rg = 0; rg < 4; rg++) {
        int r = rt * 16 + q * 4 + rg;
        sC[r * HH + wv * 32 + ct * 16 + m] = f2bf(acc[rt][ct][rg]);
      }
  __syncthreads();
  for (int i = tid; i < rows * 16; i += 256) {
    int r = i >> 4, g = i & 15;
    ((uint4*)(outb + (size_t)(row0 + r) * HH))[g] = ((const uint4*)(sC + r * HH))[g];
  }
}

// ---------------- outb[M][128] (bf16) = A[M][128] @ W^T via MFMA (xsum, y)
__global__ __launch_bounds__(256, 4) void k_gemm128b(const float* __restrict__ A,
                                                     const unsigned short* __restrict__ Wbf,
                                                     unsigned short* __restrict__ outb, int M) {
  __shared__ unsigned short sA[64 * SB];
  int tid = threadIdx.x, lane = tid & 63, wv = tid >> 6;
  int row0 = blockIdx.x * 64;
  int rows = min(64, M - row0);
  bf16x8 bfrag[2][4];
  load_bfrags(Wbf, wv, lane, bfrag);
#pragma unroll
  for (int it = 0; it < 4; it++) {
    int g = it * 2048 + tid * 8;
    int r = g >> 7, c = g & 127;
    bf16x8 v = {0, 0, 0, 0, 0, 0, 0, 0};
    if (r < rows) {
      float4 f0 = *(const float4*)(A + (size_t)(row0 + r) * HH + c);
      float4 f1 = *(const float4*)(A + (size_t)(row0 + r) * HH + c + 4);
      v[0] = (short)f2bf(f0.x); v[1] = (short)f2bf(f0.y);
      v[2] = (short)f2bf(f0.z); v[3] = (short)f2bf(f0.w);
      v[4] = (short)f2bf(f1.x); v[5] = (short)f2bf(f1.y);
      v[6] = (short)f2bf(f1.z); v[7] = (short)f2bf(f1.w);
    }
    *(bf16x8*)(&sA[r * SB + c]) = v;
  }
  __syncthreads();
  int m = lane & 15, q = lane >> 4;
  f32x4 acc[4][2];
#pragma unroll
  for (int rt = 0; rt < 4; rt++)
#pragma unroll
    for (int ct = 0; ct < 2; ct++) acc[rt][ct] = (f32x4){0.f, 0.f, 0.f, 0.f};
#pragma unroll
  for (int kt = 0; kt < 4; kt++) {
    int kof = kt * 32 + q * 8;
#pragma unroll
    for (int rt = 0; rt < 4; rt++) {
      bf16x8 af = *(const bf16x8*)(&sA[(rt * 16 + m) * SB + kof]);
      acc[rt][0] = __builtin_amdgcn_mfma_f32_16x16x32_bf16(af, bfrag[0][kt], acc[rt][0], 0, 0, 0);
      acc[rt][1] = __builtin_amdgcn_mfma_f32_16x16x32_bf16(af, bfrag[1][kt], acc[rt][1], 0, 0, 0);
    }
  }
  __syncthreads();
  unsigned short* sC = sA;
#pragma unroll
  for (int rt = 0; rt < 4; rt++)
#pragma unroll
    for (int ct = 0; ct < 2; ct++)
#pragma unroll
      for (int rg = 0; rg < 4; rg++) {
        int r = rt * 16 + q * 4 + rg;
        sC[r * HH + wv * 32 + ct * 16 + m] = f2bf(acc[rt][ct][rg]);
      }
  __syncthreads();
  for (int i = tid; i < rows * 16; i += 256) {
    int r = i >> 4, g = i & 15;
    ((uint4*)(outb + (size_t)(row0 + r) * HH))[g] = ((const uint4*)(sC + r * HH))[g];
  }
}

// ---------------- bnd via linear boundary marking + dme1 histogram (fused)
__global__ __launch_bounds__(256) void k_bounds_hist(const int* __restrict__ ii,
                                                     int* __restrict__ bnd,
                                                     const int* __restrict__ dme1,
                                                     int* __restrict__ cnt) {
  int j = blockIdx.x * 256 + threadIdx.x;
  if (j < cE_DOM) atomicAdd(&cnt[dme1[j]], 1);
  if (j > cE_NODE) return;
  if (j == cE_NODE) {
    int a = ii[cE_NODE - 1];
    for (int e = a + 1; e <= cN_INT; ++e) bnd[e] = cE_NODE;
    return;
  }
  int b = ii[j];
  int a = (j == 0) ? -1 : ii[j - 1];
  for (int e = a + 1; e <= b; ++e) bnd[e] = j;
}

// ---------------- CSR build: offs + per-position records {s, t, j0, n}
__global__ __launch_bounds__(256) void k_scan1(const int* __restrict__ cnt,
                                               int* __restrict__ bsum, int* __restrict__ excl) {
  __shared__ int buf[256];
  int i = blockIdx.x * 256 + threadIdx.x;
  int v = (i < cN_SRC) ? cnt[i] : 0;
  buf[threadIdx.x] = v; __syncthreads();
  for (int d = 1; d < 256; d <<= 1) {
    int t = (threadIdx.x >= d) ? buf[threadIdx.x - d] : 0;
    __syncthreads();
    buf[threadIdx.x] += t;
    __syncthreads();
  }
  if (i < cN_SRC) excl[i] = buf[threadIdx.x] - v;
  if (threadIdx.x == 255) bsum[blockIdx.x] = buf[255];
}
__global__ __launch_bounds__(256) void k_scan2(int* __restrict__ bsum, int nb) {
  __shared__ int buf[256];
  int v = (threadIdx.x < nb) ? bsum[threadIdx.x] : 0;
  buf[threadIdx.x] = v; __syncthreads();
  for (int d = 1; d < 256; d <<= 1) {
    int t = (threadIdx.x >= d) ? buf[threadIdx.x - d] : 0;
    __syncthreads();
    buf[threadIdx.x] += t;
    __syncthreads();
  }
  if (threadIdx.x < nb) bsum[threadIdx.x] = buf[threadIdx.x] - v;
}
__global__ void k_scan3(const int* __restrict__ excl, const int* __restrict__ bsum,
                        int* __restrict__ offs, int* __restrict__ cursor) {
  int i = blockIdx.x * 256 + threadIdx.x;
  if (i < cN_SRC) { int o = excl[i] + bsum[i >> 8]; offs[i] = o; cursor[i] = o; }
  else if (i == cN_SRC) offs[cN_SRC] = cE_DOM;
}
// scatter: pre-gather ALL per-edge metadata into CSR position order while the
// e-indexed reads are still coalesced.
__global__ void k_scatter(const int* __restrict__ dme0, const int* __restrict__ dme1,
                          const int* __restrict__ bnd, int* __restrict__ cursor,
                          int4* __restrict__ rec) {
  int e = blockIdx.x * blockDim.x + threadIdx.x;
  if (e < cE_DOM) {
    int t = dme1[e];
    int pos = atomicAdd(&cursor[t], 1);
    int j0 = bnd[e];
    rec[pos] = make_int4(dme0[e], t, j0, bnd[e + 1] - j0);
  }
}

// ---------------- edge kernel v6: CSR-position order, wave-per-edge (8/wave).
// MLP restored by force: BRANCHLESS gathers (clamp to row 0, select-zero on
// accumulate) so no basic-block boundaries block batching, plus
// sched_barrier(0) pins so the scheduler cannot re-serialize the pipeline
// (v5 evidence: VGPR_Count=28 proved loads were sunk to just-before-use).
#define EDGE_ISSUE(I, B)                                                     \
  do {                                                                       \
    int le_ = wv * 8 + (I);                                                  \
    int n_ = __builtin_amdgcn_readfirstlane(sR[le_].w);                      \
    _Pragma("unroll")                                                        \
    for (int k_ = 0; k_ < 4; k_++) {                                         \
      int r_ = (k_ < n_) ? __builtin_amdgcn_readlane(idxv[I], k_) : 0;       \
      ub[B][k_] = xwu[(size_t)r_ * 64 + lane];                               \
    }                                                                        \
  } while (0)

#define EDGE_CONSUME(I, B)                                                   \
  do {                                                                       \
    int le_ = wv * 8 + (I);                                                  \
    int j0_ = __builtin_amdgcn_readfirstlane(sR[le_].z);                     \
    int n_ = __builtin_amdgcn_readfirstlane(sR[le_].w);                      \
    float a0_ = 0.f, a1_ = 0.f;                                              \
    _Pragma("unroll")                                                        \
    for (int k_ = 0; k_ < 4; k_++) {                                         \
      unsigned uv_ = (k_ < n_) ? ub[B][k_] : 0u;                             \
      a0_ += bf2f(uv_ & 0xffff);                                             \
      a1_ += bf2f(uv_ >> 16);                                                \
    }                                                                        \
    if (n_ > 4) {                                                            \
      for (int k_ = 4; k_ < n_; k_++) {                                      \
        int r_ = (k_ < 64) ? __builtin_amdgcn_readlane(idxv[I], k_)          \
                           : nme0[j0_ + k_];                                 \
        unsigned uu_ = xwu[(size_t)r_ * 64 + lane];                          \
        a0_ += bf2f(uu_ & 0xffff);                                           \
        a1_ += bf2f(uu_ >> 16);                                              \
      }                                                                      \
    }                                                                        \
    float m0_ = a0_ + bf2f(xs[I] & 0xffff) + bf2f(yy[I] & 0xffff);           \
    float m1_ = a1_ + bf2f(xs[I] >> 16) + bf2f(yy[I] >> 16);                 \
    unsigned um_ = ((unsigned)f2bf(m1_) << 16) | (unsigned)f2bf(m0_);        \
    __builtin_nontemporal_store(um_, &msgu[(size_t)(e0 + le_) * 64 + lane]); \
    s0 += m0_; q0 += m0_ * m0_; s1 += m1_; q1 += m1_ * m1_;                  \
  } while (0)

#define SBAR __builtin_amdgcn_sched_barrier(0)

__global__ __launch_bounds__(256, 8) void k_edge2(
    const unsigned* __restrict__ xwu, const int* __restrict__ nme0,
    const unsigned* __restrict__ xslu, const unsigned* __restrict__ ylu,
    const int4* __restrict__ rec,
    unsigned* __restrict__ msgu, float* __restrict__ part2) {
  __shared__ int4 sR[32];
  __shared__ float sBN[1024];
  int tid = threadIdx.x, lane = tid & 63, wv = tid >> 6;
  int e0 = blockIdx.x * 32;
  if (tid < 32) sR[tid] = rec[e0 + tid];
  __syncthreads();

  // Phase A: issue xs/yy/idxv for all 8 edges (24 independent loads in flight)
  unsigned xs[8], yy[8];
  int idxv[8];
#pragma unroll
  for (int i = 0; i < 8; i++) {
    int le = wv * 8 + i;
    int s  = __builtin_amdgcn_readfirstlane(sR[le].x);
    int t  = __builtin_amdgcn_readfirstlane(sR[le].y);
    int j0 = __builtin_amdgcn_readfirstlane(sR[le].z);
    int n  = __builtin_amdgcn_readfirstlane(sR[le].w);
    xs[i] = xslu[(size_t)s * 64 + lane];
    yy[i] = ylu[(size_t)t * 64 + lane];
    idxv[i] = (lane < n) ? nme0[j0 + lane] : 0;
  }
  SBAR;

  float s0 = 0.f, q0 = 0.f, s1 = 0.f, q1 = 0.f;
  unsigned ub[3][4];
  EDGE_ISSUE(0, 0); SBAR;
  EDGE_ISSUE(1, 1); SBAR;
  EDGE_ISSUE(2, 2); SBAR;
  EDGE_CONSUME(0, 0);
  EDGE_ISSUE(3, 0); SBAR;
  EDGE_CONSUME(1, 1);
  EDGE_ISSUE(4, 1); SBAR;
  EDGE_CONSUME(2, 2);
  EDGE_ISSUE(5, 2); SBAR;
  EDGE_CONSUME(3, 0);
  EDGE_ISSUE(6, 0); SBAR;
  EDGE_CONSUME(4, 1);
  EDGE_ISSUE(7, 1); SBAR;
  EDGE_CONSUME(5, 2);
  EDGE_CONSUME(6, 0);
  EDGE_CONSUME(7, 1);

  *(float4*)(&sBN[wv * 256 + lane * 4]) = make_float4(s0, q0, s1, q1);
  __syncthreads();
  float v = sBN[tid] + sBN[256 + tid] + sBN[512 + tid] + sBN[768 + tid];
  atomicAdd(&part2[((blockIdx.x & 63) << 8) + tid], v);
}

// ---------------- BN stat finalize: sum the 64 spread slots + scale/shift
__global__ __launch_bounds__(256) void k_bnfinal(const float* __restrict__ part2,
                                                 const float* __restrict__ bnw,
                                                 const float* __restrict__ bnb,
                                                 float* __restrict__ ss) {
  __shared__ float L[256];
  float s = 0.f;
  for (int b = 0; b < 64; b++) s += part2[b * 256 + threadIdx.x];
  L[threadIdx.x] = s; __syncthreads();
  if (threadIdx.x < HH) {
    int c = threadIdx.x;
    float sum = L[2 * c], sq = L[2 * c + 1];
    float mean = sum / (float)cE_DOM;
    float var = sq / (float)cE_DOM - mean * mean;
    float sc = bnw[c] * rsqrtf(var + 1e-5f);
    float sh = bnb[c] - mean * sc;
    ss[2 * c] = sc; ss[2 * c + 1] = sh;
  }
}

// ---------------- final: msg is CSR-ordered, so each target reads a
// CONTIGUOUS run of rows [offs[t], offs[t+1]). 8-deep load batching,
// sched_barrier-pinned so the batch stays batched.
__global__ __launch_bounds__(256, 8) void k_out2(const unsigned* __restrict__ msgu,
                                                 const int* __restrict__ offs,
                                                 const float* __restrict__ ss,
                                                 float* __restrict__ out) {
  int wv = threadIdx.x >> 6, lane = threadIdx.x & 63;
  int t = blockIdx.x * 4 + wv;
  if (t >= cN_Y) return;
  int c0 = lane * 2;
  float sc0 = ss[c0 * 2 + 0], sh0 = ss[c0 * 2 + 1];
  float sc1 = ss[c0 * 2 + 2], sh1 = ss[c0 * 2 + 3];
  int j0 = __builtin_amdgcn_readfirstlane(offs[t]);
  int j1 = __builtin_amdgcn_readfirstlane(offs[t + 1]);
  float a0 = 0.f, a1 = 0.f;
  int p = j0;
  for (; p + 8 <= j1; p += 8) {
    unsigned m[8];
#pragma unroll
    for (int k = 0; k < 8; k++) m[k] = msgu[(size_t)(p + k) * 64 + lane];
    __builtin_amdgcn_sched_barrier(0);
#pragma unroll
    for (int k = 0; k < 8; k++) {
      a0 += fmaxf(fmaf(bf2f(m[k] & 0xffff), sc0, sh0), 0.f);
      a1 += fmaxf(fmaf(bf2f(m[k] >> 16), sc1, sh1), 0.f);
    }
  }
  if (p + 4 <= j1) {
    unsigned m[4];
#pragma unroll
    for (int k = 0; k < 4; k++) m[k] = msgu[(size_t)(p + k) * 64 + lane];
    __builtin_amdgcn_sched_barrier(0);
#pragma unroll
    for (int k = 0; k < 4; k++) {
      a0 += fmaxf(fmaf(bf2f(m[k] & 0xffff), sc0, sh0), 0.f);
      a1 += fmaxf(fmaf(bf2f(m[k] >> 16), sc1, sh1), 0.f);
    }
    p += 4;
  }
  for (; p < j1; p++) {
    unsigned m = msgu[(size_t)p * 64 + lane];
    a0 += fmaxf(fmaf(bf2f(m & 0xffff), sc0, sh0), 0.f);
    a1 += fmaxf(fmaf(bf2f(m >> 16), sc1, sh1), 0.f);
  }
  *(float2*)(out + (size_t)t * HH + c0) = make_float2(a0, a1);
}

extern "C" void kernel_launch(void* const* d_in, const int* in_sizes, int n_in,
                              void* d_out, int out_size, void* d_ws, size_t ws_size,
                              hipStream_t stream) {
  const float* x     = (const float*)d_in[0];
  const float* y     = (const float*)d_in[1];
  const int* dom_ind = (const int*)d_in[2];
  const int* nme     = (const int*)d_in[3];
  const int* ii      = (const int*)d_in[4];
  const int* dme     = (const int*)d_in[5];
  const float* Wxsum = (const float*)d_in[6];
  const float* Wxint = (const float*)d_in[7];
  const float* Wy    = (const float*)d_in[8];
  const float* bnw   = (const float*)d_in[9];
  const float* bnb   = (const float*)d_in[10];
  float* out = (float*)d_out;

  char* ws = (char*)d_ws;
  size_t o = 0;
  auto alloc = [&](size_t bytes) -> void* {
    void* p = ws + o;
    o = (o + bytes + 255) & ~(size_t)255;
    return p;
  };
  float* xsum   = (float*)alloc((size_t)cN_SRC * HH * 4);
  unsigned short* xsl = (unsigned short*)alloc((size_t)cN_SRC * HH * 2);
  unsigned short* ylin = (unsigned short*)alloc((size_t)cN_Y * HH * 2);
  unsigned short* xw = (unsigned short*)alloc((size_t)cN_X * HH * 2);
  unsigned short* msg = (unsigned short*)alloc((size_t)cE_DOM * HH * 2);
  int* bnd      = (int*)alloc((size_t)(cN_INT + 1) * 4);
  int* cnt      = (int*)alloc((size_t)cN_SRC * 4);
  int* excl     = (int*)alloc((size_t)cN_SRC * 4);
  int* bsum     = (int*)alloc(256 * 4);
  int* offs     = (int*)alloc((size_t)(cN_SRC + 1) * 4);
  int* cursor   = (int*)alloc((size_t)cN_SRC * 4);
  int4* rec     = (int4*)alloc((size_t)cE_DOM * 16);
  float* part2  = (float*)alloc(64 * 256 * 4);
  float* ssbuf  = (float*)alloc(256 * 4);
  unsigned short* Wbf = (unsigned short*)alloc(3 * 16384 * 2);

  hipMemsetAsync(xsum, 0, (size_t)cN_SRC * HH * 4, stream);
  hipMemsetAsync(cnt, 0, (size_t)cN_SRC * 4, stream);
  hipMemsetAsync(part2, 0, 64 * 256 * 4, stream);

  k_wcast<<<48, 256, 0, stream>>>(Wxsum, Wy, Wxint, Wbf);
  k_gemmx_segsum<<<(cN_X + 63) / 64, 256, 0, stream>>>(x, dom_ind, Wbf + 32768, xw, xsum);
  k_gemm128b<<<(cN_SRC + 63) / 64, 256, 0, stream>>>(xsum, Wbf, xsl, cN_SRC);
  k_gemm128b<<<(cN_Y + 63) / 64, 256, 0, stream>>>(y, Wbf + 16384, ylin, cN_Y);
  k_bounds_hist<<<(cE_NODE + 1 + 255) / 256, 256, 0, stream>>>(ii, bnd, dme + cE_DOM, cnt);
  k_scan1<<<(cN_SRC + 255) / 256, 256, 0, stream>>>(cnt, bsum, excl);
  k_scan2<<<1, 256, 0, stream>>>(bsum, (cN_SRC + 255) / 256);
  k_scan3<<<(cN_SRC + 1 + 255) / 256, 256, 0, stream>>>(excl, bsum, offs, cursor);
  k_scatter<<<(cE_DOM + 255) / 256, 256, 0, stream>>>(dme, dme + cE_DOM, bnd, cursor, rec);
  k_edge2<<<cE_DOM / 32, 256, 0, stream>>>((const unsigned*)xw, nme,
                                           (const unsigned*)xsl, (const unsigned*)ylin,
                                           rec, (unsigned*)msg, part2);
  k_bnfinal<<<1, 256, 0, stream>>>(part2, bnw, bnb, ssbuf);
  k_out2<<<(cN_Y + 3) / 4, 256, 0, stream>>>((const unsigned*)msg, offs, ssbuf, out);
}

// Round 5
// 425.668 us; speedup vs baseline: 1.4942x; 1.0536x over previous
//
#include <hip/hip_runtime.h>
#include <cstdint>

#define HH 128
#define SB 136  // padded bf16 LDS row stride for GEMM A tiles (272 B: 16B-aligned, 2-way max bank alias)
constexpr int cN_X   = 250000;
constexpr int cN_SRC = 50000;
constexpr int cN_Y   = 50000;
constexpr int cN_INT = 500000;
constexpr int cE_NODE = 1000000;
constexpr int cE_DOM  = 500000;

typedef __attribute__((ext_vector_type(8))) short bf16x8;
typedef __attribute__((ext_vector_type(4))) float f32x4;

__device__ __forceinline__ float bf2f(unsigned short s) {
  union { unsigned u; float f; } v; v.u = ((unsigned)s) << 16; return v.f;
}
__device__ __forceinline__ unsigned short f2bf(float f) {
  union { float f; unsigned u; } v; v.f = f;
  unsigned r = v.u + 0x7fffu + ((v.u >> 16) & 1u);  // RNE
  return (unsigned short)(r >> 16);
}

// ---------------- setup mega-kernel: wcast + zero(xsum,cnt,part2) + bounds.
// All regions mutually independent; consumers are in LATER dispatches.
// blocks: [0,48) wcast | [48,6298) zero xsum | [6298,6347) zero cnt |
//         [6347,6363) zero part2 | [6363,10270) bounds
__global__ __launch_bounds__(256) void k_setup(const float* __restrict__ w0,
                                               const float* __restrict__ w1,
                                               const float* __restrict__ w2,
                                               unsigned short* __restrict__ dst,
                                               const int* __restrict__ ii,
                                               int* __restrict__ bnd,
                                               float* __restrict__ xsum,
                                               int* __restrict__ cnt,
                                               float* __restrict__ part2) {
  int b = blockIdx.x, tid = threadIdx.x;
  if (b < 48) {  // wcast: 3 x 128x128 f32 -> bf16
    int i = b * 256 + tid;
    int idx4 = i * 4;
    int mat = idx4 >> 14;
    int off = idx4 & 16383;
    const float* src = (mat == 0) ? w0 : (mat == 1) ? w1 : w2;
    float4 v = *(const float4*)(src + off);
    ushort4 u;
    u.x = f2bf(v.x); u.y = f2bf(v.y); u.z = f2bf(v.z); u.w = f2bf(v.w);
    *(ushort4*)(dst + (size_t)mat * 16384 + off) = u;
    return;
  }
  b -= 48;
  if (b < 6250) {  // zero xsum: 6.4M floats = 1.6M float4
    ((float4*)xsum)[(size_t)b * 256 + tid] = make_float4(0.f, 0.f, 0.f, 0.f);
    return;
  }
  b -= 6250;
  if (b < 49) {  // zero cnt: 50000 ints = 12500 int4
    int i = b * 256 + tid;
    if (i < 12500) ((int4*)cnt)[i] = make_int4(0, 0, 0, 0);
    return;
  }
  b -= 49;
  if (b < 16) {  // zero part2: 16384 floats = 4096 float4
    ((float4*)part2)[b * 256 + tid] = make_float4(0.f, 0.f, 0.f, 0.f);
    return;
  }
  b -= 16;
  {  // bounds: bnd[e] = first j with ii[j] >= e
    int j = b * 256 + tid;
    if (j > cE_NODE) return;
    if (j == cE_NODE) {
      int a = ii[cE_NODE - 1];
      for (int e = a + 1; e <= cN_INT; ++e) bnd[e] = cE_NODE;
      return;
    }
    int bb = ii[j];
    int a = (j == 0) ? -1 : ii[j - 1];
    for (int e = a + 1; e <= bb; ++e) bnd[e] = j;
  }
}

// ---------------- MFMA helpers
__device__ __forceinline__ void load_bfrags(const unsigned short* __restrict__ Wbf,
                                            int wv, int lane, bf16x8 bfrag[2][4]) {
  int cbase = wv * 32 + (lane & 15);
  int krow = (lane >> 4) * 8;
#pragma unroll
  for (int ct = 0; ct < 2; ct++)
#pragma unroll
    for (int kt = 0; kt < 4; kt++)
      bfrag[ct][kt] = *(const bf16x8*)(Wbf + (size_t)(cbase + ct * 16) * HH + kt * 32 + krow);
}

// ---------------- fused: xw = x @ Wxint^T  AND  xsum += segsum(x)  AND  dme1 hist.
// Hist prologue is race-free: cnt zeroed in the PRIOR k_setup dispatch; scan1
// (the consumer) runs in a LATER dispatch. Segsum reads the staged bf16 LDS tile.
__global__ __launch_bounds__(256, 4) void k_gemmx_segsum(
    const float* __restrict__ A, const int* __restrict__ ind,
    const unsigned short* __restrict__ Wbf,
    unsigned short* __restrict__ outb, float* __restrict__ xsum,
    const int* __restrict__ dme1, int* __restrict__ cnt) {
  __shared__ unsigned short sA[64 * SB];
  __shared__ int sind[64];
  int tid = threadIdx.x, lane = tid & 63, wv = tid >> 6;
  {  // fused histogram of dme1 (grid 3907 x 256 covers 500K with guard)
    int e = blockIdx.x * 256 + tid;
    if (e < cE_DOM) atomicAdd(&cnt[dme1[e]], 1);
  }
  int row0 = blockIdx.x * 64;
  int rows = min(64, cN_X - row0);
  if (tid < 64 && tid < rows) sind[tid] = ind[row0 + tid];
  bf16x8 bfrag[2][4];
  load_bfrags(Wbf, wv, lane, bfrag);
  // stage 64x128 f32 -> bf16 LDS
#pragma unroll
  for (int it = 0; it < 4; it++) {
    int g = it * 2048 + tid * 8;
    int r = g >> 7, c = g & 127;
    bf16x8 v = {0, 0, 0, 0, 0, 0, 0, 0};
    if (r < rows) {
      float4 f0 = *(const float4*)(A + (size_t)(row0 + r) * HH + c);
      float4 f1 = *(const float4*)(A + (size_t)(row0 + r) * HH + c + 4);
      v[0] = (short)f2bf(f0.x); v[1] = (short)f2bf(f0.y);
      v[2] = (short)f2bf(f0.z); v[3] = (short)f2bf(f0.w);
      v[4] = (short)f2bf(f1.x); v[5] = (short)f2bf(f1.y);
      v[6] = (short)f2bf(f1.z); v[7] = (short)f2bf(f1.w);
    }
    *(bf16x8*)(&sA[r * SB + c]) = v;
  }
  __syncthreads();
  // ---- segment-sum side: wave wv owns rows [wv*16, wv*16+16), lane = col pair
  {
    int rbase = wv * 16;
    if (rbase < rows) {
      int nr = min(16, rows - rbase);
      int c0 = lane * 2;
      unsigned xv[16];
#pragma unroll
      for (int k = 0; k < 16; k++)
        xv[k] = (k < nr) ? *(const unsigned*)(&sA[(rbase + k) * SB + c0]) : 0u;
      float a0 = 0.f, a1 = 0.f;
      int cur = sind[rbase];
      bool inside = false;
#pragma unroll
      for (int k = 0; k < 16; k++) {
        if (k < nr) {
          int s = sind[rbase + k];
          if (s != cur) {
            if (inside) {
              xsum[(size_t)cur * HH + c0] = a0;
              xsum[(size_t)cur * HH + c0 + 1] = a1;
            } else {
              atomicAdd(&xsum[(size_t)cur * HH + c0], a0);
              atomicAdd(&xsum[(size_t)cur * HH + c0 + 1], a1);
            }
            cur = s; a0 = 0.f; a1 = 0.f; inside = true;
          }
          a0 += bf2f(xv[k] & 0xffff); a1 += bf2f(xv[k] >> 16);
        }
      }
      atomicAdd(&xsum[(size_t)cur * HH + c0], a0);
      atomicAdd(&xsum[(size_t)cur * HH + c0 + 1], a1);
    }
  }
  // ---- MFMA side
  int m = lane & 15, q = lane >> 4;
  f32x4 acc[4][2];
#pragma unroll
  for (int rt = 0; rt < 4; rt++)
#pragma unroll
    for (int ct = 0; ct < 2; ct++) acc[rt][ct] = (f32x4){0.f, 0.f, 0.f, 0.f};
#pragma unroll
  for (int kt = 0; kt < 4; kt++) {
    int kof = kt * 32 + q * 8;
#pragma unroll
    for (int rt = 0; rt < 4; rt++) {
      bf16x8 af = *(const bf16x8*)(&sA[(rt * 16 + m) * SB + kof]);
      acc[rt][0] = __builtin_amdgcn_mfma_f32_16x16x32_bf16(af, bfrag[0][kt], acc[rt][0], 0, 0, 0);
      acc[rt][1] = __builtin_amdgcn_mfma_f32_16x16x32_bf16(af, bfrag[1][kt], acc[rt][1], 0, 0, 0);
    }
  }
  __syncthreads();
  unsigned short* sC = sA;
#pragma unroll
  for (int rt = 0; rt < 4; rt++)
#pragma unroll
    for (int ct = 0; ct < 2; ct++)
#pragma unroll
      for (int rg = 0; rg < 4; rg++) {
        int r = rt * 16 + q * 4 + rg;
        sC[r * HH + wv * 32 + ct * 16 + m] = f2bf(acc[rt][ct][rg]);
      }
  __syncthreads();
  for (int i = tid; i < rows * 16; i += 256) {
    int r = i >> 4, g = i & 15;
    ((uint4*)(outb + (size_t)(row0 + r) * HH))[g] = ((const uint4*)(sC + r * HH))[g];
  }
}

// ---------------- both 50K-row GEMMs in ONE launch: blocks [0,782) -> xsl,
// [782,1564) -> ylin.
__global__ __launch_bounds__(256, 4) void k_gemm2(const float* __restrict__ Axs,
                                                  const float* __restrict__ Ay,
                                                  const unsigned short* __restrict__ Wbf,
                                                  unsigned short* __restrict__ xsl,
                                                  unsigned short* __restrict__ ylin) {
  __shared__ unsigned short sA[64 * SB];
  int tid = threadIdx.x, lane = tid & 63, wv = tid >> 6;
  const int nbm = (cN_SRC + 63) / 64;  // 782
  bool isY = blockIdx.x >= nbm;
  const float* A = isY ? Ay : Axs;
  const unsigned short* W = Wbf + (isY ? 16384 : 0);
  unsigned short* outb = isY ? ylin : xsl;
  int bb = isY ? blockIdx.x - nbm : blockIdx.x;
  int row0 = bb * 64;
  int rows = min(64, cN_SRC - row0);
  bf16x8 bfrag[2][4];
  load_bfrags(W, wv, lane, bfrag);
#pragma unroll
  for (int it = 0; it < 4; it++) {
    int g = it * 2048 + tid * 8;
    int r = g >> 7, c = g & 127;
    bf16x8 v = {0, 0, 0, 0, 0, 0, 0, 0};
    if (r < rows) {
      float4 f0 = *(const float4*)(A + (size_t)(row0 + r) * HH + c);
      float4 f1 = *(const float4*)(A + (size_t)(row0 + r) * HH + c + 4);
      v[0] = (short)f2bf(f0.x); v[1] = (short)f2bf(f0.y);
      v[2] = (short)f2bf(f0.z); v[3] = (short)f2bf(f0.w);
      v[4] = (short)f2bf(f1.x); v[5] = (short)f2bf(f1.y);
      v[6] = (short)f2bf(f1.z); v[7] = (short)f2bf(f1.w);
    }
    *(bf16x8*)(&sA[r * SB + c]) = v;
  }
  __syncthreads();
  int m = lane & 15, q = lane >> 4;
  f32x4 acc[4][2];
#pragma unroll
  for (int rt = 0; rt < 4; rt++)
#pragma unroll
    for (int ct = 0; ct < 2; ct++) acc[rt][ct] = (f32x4){0.f, 0.f, 0.f, 0.f};
#pragma unroll
  for (int kt = 0; kt < 4; kt++) {
    int kof = kt * 32 + q * 8;
#pragma unroll
    for (int rt = 0; rt < 4; rt++) {
      bf16x8 af = *(const bf16x8*)(&sA[(rt * 16 + m) * SB + kof]);
      acc[rt][0] = __builtin_amdgcn_mfma_f32_16x16x32_bf16(af, bfrag[0][kt], acc[rt][0], 0, 0, 0);
      acc[rt][1] = __builtin_amdgcn_mfma_f32_16x16x32_bf16(af, bfrag[1][kt], acc[rt][1], 0, 0, 0);
    }
  }
  __syncthreads();
  unsigned short* sC = sA;
#pragma unroll
  for (int rt = 0; rt < 4; rt++)
#pragma unroll
    for (int ct = 0; ct < 2; ct++)
#pragma unroll
      for (int rg = 0; rg < 4; rg++) {
        int r = rt * 16 + q * 4 + rg;
        sC[r * HH + wv * 32 + ct * 16 + m] = f2bf(acc[rt][ct][rg]);
      }
  __syncthreads();
  for (int i = tid; i < rows * 16; i += 256) {
    int r = i >> 4, g = i & 15;
    ((uint4*)(outb + (size_t)(row0 + r) * HH))[g] = ((const uint4*)(sC + r * HH))[g];
  }
}

// ---------------- CSR build
__global__ __launch_bounds__(256) void k_scan1(const int* __restrict__ cnt,
                                               int* __restrict__ bsum, int* __restrict__ excl) {
  __shared__ int buf[256];
  int i = blockIdx.x * 256 + threadIdx.x;
  int v = (i < cN_SRC) ? cnt[i] : 0;
  buf[threadIdx.x] = v; __syncthreads();
  for (int d = 1; d < 256; d <<= 1) {
    int t = (threadIdx.x >= d) ? buf[threadIdx.x - d] : 0;
    __syncthreads();
    buf[threadIdx.x] += t;
    __syncthreads();
  }
  if (i < cN_SRC) excl[i] = buf[threadIdx.x] - v;
  if (threadIdx.x == 255) bsum[blockIdx.x] = buf[255];
}
// scan2+scan3 fused: every block redundantly scans the 196 block sums (tiny,
// read-only bsum) in LDS, then applies its 256 elements.
__global__ __launch_bounds__(256) void k_scan23(const int* __restrict__ excl,
                                                const int* __restrict__ bsum,
                                                int* __restrict__ offs,
                                                int* __restrict__ cursor, int nb) {
  __shared__ int buf[256];
  __shared__ int ex[256];
  int tid = threadIdx.x;
  int v = (tid < nb) ? bsum[tid] : 0;
  buf[tid] = v; __syncthreads();
  for (int d = 1; d < 256; d <<= 1) {
    int t = (tid >= d) ? buf[tid - d] : 0;
    __syncthreads();
    buf[tid] += t;
    __syncthreads();
  }
  ex[tid] = buf[tid] - v;
  __syncthreads();
  int i = blockIdx.x * 256 + tid;
  if (i < cN_SRC) { int o = excl[i] + ex[i >> 8]; offs[i] = o; cursor[i] = o; }
  else if (i == cN_SRC) offs[cN_SRC] = cE_DOM;
}
// scatter: pre-gather ALL per-edge metadata into CSR position order
__global__ void k_scatter(const int* __restrict__ dme0, const int* __restrict__ dme1,
                          const int* __restrict__ bnd, int* __restrict__ cursor,
                          int4* __restrict__ rec) {
  int e = blockIdx.x * blockDim.x + threadIdx.x;
  if (e < cE_DOM) {
    int t = dme1[e];
    int pos = atomicAdd(&cursor[t], 1);
    int j0 = bnd[e];
    rec[pos] = make_int4(dme0[e], t, j0, bnd[e + 1] - j0);
  }
}

// ---------------- edge kernel (unchanged from verified round-4 version)
#define EDGE_ISSUE(I, B)                                                     \
  do {                                                                       \
    int le_ = wv * 8 + (I);                                                  \
    int n_ = __builtin_amdgcn_readfirstlane(sR[le_].w);                      \
    _Pragma("unroll")                                                        \
    for (int k_ = 0; k_ < 4; k_++) {                                         \
      int r_ = (k_ < n_) ? __builtin_amdgcn_readlane(idxv[I], k_) : 0;       \
      ub[B][k_] = xwu[(size_t)r_ * 64 + lane];                               \
    }                                                                        \
  } while (0)

#define EDGE_CONSUME(I, B)                                                   \
  do {                                                                       \
    int le_ = wv * 8 + (I);                                                  \
    int j0_ = __builtin_amdgcn_readfirstlane(sR[le_].z);                     \
    int n_ = __builtin_amdgcn_readfirstlane(sR[le_].w);                      \
    float a0_ = 0.f, a1_ = 0.f;                                              \
    _Pragma("unroll")                                                        \
    for (int k_ = 0; k_ < 4; k_++) {                                         \
      unsigned uv_ = (k_ < n_) ? ub[B][k_] : 0u;                             \
      a0_ += bf2f(uv_ & 0xffff);                                             \
      a1_ += bf2f(uv_ >> 16);                                                \
    }                                                                        \
    if (n_ > 4) {                                                            \
      for (int k_ = 4; k_ < n_; k_++) {                                      \
        int r_ = (k_ < 64) ? __builtin_amdgcn_readlane(idxv[I], k_)          \
                           : nme0[j0_ + k_];                                 \
        unsigned uu_ = xwu[(size_t)r_ * 64 + lane];                          \
        a0_ += bf2f(uu_ & 0xffff);                                           \
        a1_ += bf2f(uu_ >> 16);                                              \
      }                                                                      \
    }                                                                        \
    float m0_ = a0_ + bf2f(xs[I] & 0xffff) + bf2f(yy[I] & 0xffff);           \
    float m1_ = a1_ + bf2f(xs[I] >> 16) + bf2f(yy[I] >> 16);                 \
    unsigned um_ = ((unsigned)f2bf(m1_) << 16) | (unsigned)f2bf(m0_);        \
    __builtin_nontemporal_store(um_, &msgu[(size_t)(e0 + le_) * 64 + lane]); \
    s0 += m0_; q0 += m0_ * m0_; s1 += m1_; q1 += m1_ * m1_;                  \
  } while (0)

#define SBAR __builtin_amdgcn_sched_barrier(0)

__global__ __launch_bounds__(256, 8) void k_edge2(
    const unsigned* __restrict__ xwu, const int* __restrict__ nme0,
    const unsigned* __restrict__ xslu, const unsigned* __restrict__ ylu,
    const int4* __restrict__ rec,
    unsigned* __restrict__ msgu, float* __restrict__ part2) {
  __shared__ int4 sR[32];
  __shared__ float sBN[1024];
  int tid = threadIdx.x, lane = tid & 63, wv = tid >> 6;
  int e0 = blockIdx.x * 32;
  if (tid < 32) sR[tid] = rec[e0 + tid];
  __syncthreads();

  unsigned xs[8], yy[8];
  int idxv[8];
#pragma unroll
  for (int i = 0; i < 8; i++) {
    int le = wv * 8 + i;
    int s  = __builtin_amdgcn_readfirstlane(sR[le].x);
    int t  = __builtin_amdgcn_readfirstlane(sR[le].y);
    int j0 = __builtin_amdgcn_readfirstlane(sR[le].z);
    int n  = __builtin_amdgcn_readfirstlane(sR[le].w);
    xs[i] = xslu[(size_t)s * 64 + lane];
    yy[i] = ylu[(size_t)t * 64 + lane];
    idxv[i] = (lane < n) ? nme0[j0 + lane] : 0;
  }
  SBAR;

  float s0 = 0.f, q0 = 0.f, s1 = 0.f, q1 = 0.f;
  unsigned ub[3][4];
  EDGE_ISSUE(0, 0); SBAR;
  EDGE_ISSUE(1, 1); SBAR;
  EDGE_ISSUE(2, 2); SBAR;
  EDGE_CONSUME(0, 0);
  EDGE_ISSUE(3, 0); SBAR;
  EDGE_CONSUME(1, 1);
  EDGE_ISSUE(4, 1); SBAR;
  EDGE_CONSUME(2, 2);
  EDGE_ISSUE(5, 2); SBAR;
  EDGE_CONSUME(3, 0);
  EDGE_ISSUE(6, 0); SBAR;
  EDGE_CONSUME(4, 1);
  EDGE_ISSUE(7, 1); SBAR;
  EDGE_CONSUME(5, 2);
  EDGE_CONSUME(6, 0);
  EDGE_CONSUME(7, 1);

  *(float4*)(&sBN[wv * 256 + lane * 4]) = make_float4(s0, q0, s1, q1);
  __syncthreads();
  float v = sBN[tid] + sBN[256 + tid] + sBN[512 + tid] + sBN[768 + tid];
  atomicAdd(&part2[((blockIdx.x & 63) << 8) + tid], v);
}

// ---------------- BN stat finalize
__global__ __launch_bounds__(256) void k_bnfinal(const float* __restrict__ part2,
                                                 const float* __restrict__ bnw,
                                                 const float* __restrict__ bnb,
                                                 float* __restrict__ ss) {
  __shared__ float L[256];
  float s = 0.f;
  for (int b = 0; b < 64; b++) s += part2[b * 256 + threadIdx.x];
  L[threadIdx.x] = s; __syncthreads();
  if (threadIdx.x < HH) {
    int c = threadIdx.x;
    float sum = L[2 * c], sq = L[2 * c + 1];
    float mean = sum / (float)cE_DOM;
    float var = sq / (float)cE_DOM - mean * mean;
    float sc = bnw[c] * rsqrtf(var + 1e-5f);
    float sh = bnb[c] - mean * sc;
    ss[2 * c] = sc; ss[2 * c + 1] = sh;
  }
}

// ---------------- final reduce (unchanged)
__global__ __launch_bounds__(256, 8) void k_out2(const unsigned* __restrict__ msgu,
                                                 const int* __restrict__ offs,
                                                 const float* __restrict__ ss,
                                                 float* __restrict__ out) {
  int wv = threadIdx.x >> 6, lane = threadIdx.x & 63;
  int t = blockIdx.x * 4 + wv;
  if (t >= cN_Y) return;
  int c0 = lane * 2;
  float sc0 = ss[c0 * 2 + 0], sh0 = ss[c0 * 2 + 1];
  float sc1 = ss[c0 * 2 + 2], sh1 = ss[c0 * 2 + 3];
  int j0 = __builtin_amdgcn_readfirstlane(offs[t]);
  int j1 = __builtin_amdgcn_readfirstlane(offs[t + 1]);
  float a0 = 0.f, a1 = 0.f;
  int p = j0;
  for (; p + 8 <= j1; p += 8) {
    unsigned m[8];
#pragma unroll
    for (int k = 0; k < 8; k++) m[k] = msgu[(size_t)(p + k) * 64 + lane];
    __builtin_amdgcn_sched_barrier(0);
#pragma unroll
    for (int k = 0; k < 8; k++) {
      a0 += fmaxf(fmaf(bf2f(m[k] & 0xffff), sc0, sh0), 0.f);
      a1 += fmaxf(fmaf(bf2f(m[k] >> 16), sc1, sh1), 0.f);
    }
  }
  if (p + 4 <= j1) {
    unsigned m[4];
#pragma unroll
    for (int k = 0; k < 4; k++) m[k] = msgu[(size_t)(p + k) * 64 + lane];
    __builtin_amdgcn_sched_barrier(0);
#pragma unroll
    for (int k = 0; k < 4; k++) {
      a0 += fmaxf(fmaf(bf2f(m[k] & 0xffff), sc0, sh0), 0.f);
      a1 += fmaxf(fmaf(bf2f(m[k] >> 16), sc1, sh1), 0.f);
    }
    p += 4;
  }
  for (; p < j1; p++) {
    unsigned m = msgu[(size_t)p * 64 + lane];
    a0 += fmaxf(fmaf(bf2f(m & 0xffff), sc0, sh0), 0.f);
    a1 += fmaxf(fmaf(bf2f(m >> 16), sc1, sh1), 0.f);
  }
  *(float2*)(out + (size_t)t * HH + c0) = make_float2(a0, a1);
}

extern "C" void kernel_launch(void* const* d_in, const int* in_sizes, int n_in,
                              void* d_out, int out_size, void* d_ws, size_t ws_size,
                              hipStream_t stream) {
  const float* x     = (const float*)d_in[0];
  const float* y     = (const float*)d_in[1];
  const int* dom_ind = (const int*)d_in[2];
  const int* nme     = (const int*)d_in[3];
  const int* ii      = (const int*)d_in[4];
  const int* dme     = (const int*)d_in[5];
  const float* Wxsum = (const float*)d_in[6];
  const float* Wxint = (const float*)d_in[7];
  const float* Wy    = (const float*)d_in[8];
  const float* bnw   = (const float*)d_in[9];
  const float* bnb   = (const float*)d_in[10];
  float* out = (float*)d_out;

  char* ws = (char*)d_ws;
  size_t o = 0;
  auto alloc = [&](size_t bytes) -> void* {
    void* p = ws + o;
    o = (o + bytes + 255) & ~(size_t)255;
    return p;
  };
  float* xsum   = (float*)alloc((size_t)cN_SRC * HH * 4);
  unsigned short* xsl = (unsigned short*)alloc((size_t)cN_SRC * HH * 2);
  unsigned short* ylin = (unsigned short*)alloc((size_t)cN_Y * HH * 2);
  unsigned short* xw = (unsigned short*)alloc((size_t)cN_X * HH * 2);
  unsigned short* msg = (unsigned short*)alloc((size_t)cE_DOM * HH * 2);
  int* bnd      = (int*)alloc((size_t)(cN_INT + 1) * 4);
  int* cnt      = (int*)alloc((size_t)cN_SRC * 4);
  int* excl     = (int*)alloc((size_t)cN_SRC * 4);
  int* bsum     = (int*)alloc(256 * 4);
  int* offs     = (int*)alloc((size_t)(cN_SRC + 1) * 4);
  int* cursor   = (int*)alloc((size_t)cN_SRC * 4);
  int4* rec     = (int4*)alloc((size_t)cE_DOM * 16);
  float* part2  = (float*)alloc(64 * 256 * 4);
  float* ssbuf  = (float*)alloc(256 * 4);
  unsigned short* Wbf = (unsigned short*)alloc(3 * 16384 * 2);

  const int nb_scan = (cN_SRC + 255) / 256;  // 196
  // setup: 48 wcast + 6250 zero-xsum + 49 zero-cnt + 16 zero-part2 + 3907 bounds
  k_setup<<<48 + 6250 + 49 + 16 + 3907, 256, 0, stream>>>(Wxsum, Wy, Wxint, Wbf,
                                                          ii, bnd, xsum, cnt, part2);
  k_gemmx_segsum<<<(cN_X + 63) / 64, 256, 0, stream>>>(x, dom_ind, Wbf + 32768, xw, xsum,
                                                       dme + cE_DOM, cnt);
  k_gemm2<<<2 * ((cN_SRC + 63) / 64), 256, 0, stream>>>(xsum, y, Wbf, xsl, ylin);
  k_scan1<<<nb_scan, 256, 0, stream>>>(cnt, bsum, excl);
  k_scan23<<<(cN_SRC + 1 + 255) / 256, 256, 0, stream>>>(excl, bsum, offs, cursor, nb_scan);
  k_scatter<<<(cE_DOM + 255) / 256, 256, 0, stream>>>(dme, dme + cE_DOM, bnd, cursor, rec);
  k_edge2<<<cE_DOM / 32, 256, 0, stream>>>((const unsigned*)xw, nme,
                                           (const unsigned*)xsl, (const unsigned*)ylin,
                                           rec, (unsigned*)msg, part2);
  k_bnfinal<<<1, 256, 0, stream>>>(part2, bnw, bnb, ssbuf);
  k_out2<<<(cN_Y + 3) / 4, 256, 0, stream>>>((const unsigned*)msg, offs, ssbuf, out);
}